// Round 16
// baseline (786.828 us; speedup 1.0000x reference)
//
#include <hip/hip_runtime.h>

typedef __bf16 bf16;
typedef __bf16 bf16x2 __attribute__((ext_vector_type(2)));
typedef __bf16 bf16x8 __attribute__((ext_vector_type(8)));
typedef __bf16 bf16x4v __attribute__((ext_vector_type(4)));
typedef float f32x4 __attribute__((ext_vector_type(4)));

constexpr int B = 4, C = 512, T = 1024, H = 8, F = 2048, L = 6;
constexpr int TP = T + 18;               // padded rows: row0 = zero, rows T+1..T+17 zero
constexpr float SCALE = 0.125f, EPS = 1e-4f;

// ---------------------------------------------------------------------------
// global -> LDS staging, 64B rows (BK=32 tiles: 32 bf16 k-slice per row)
// LDS linear; swizzle applied on the per-lane GLOBAL source (involution),
// matched by the same XOR on the ds_read side.
// ---------------------------------------------------------------------------
__device__ __forceinline__ void stage_rows(const char* g, long strideB, char* lds,
                                           int nChunks, int tid) {
  const int wave = tid >> 6, lane = tid & 63;
  for (int c = wave; c < nChunks; c += 4) {
    int row = (c << 4) + (lane >> 2);
    int kq = (lane & 3) ^ ((row >> 1) & 3);
    const char* src = g + (long)row * strideB + kq * 16;
    char* dst = lds + ((long)c << 10);
    __builtin_amdgcn_global_load_lds((const __attribute__((address_space(1))) void*)src,
                                     (__attribute__((address_space(3))) void*)dst,
                                     16, 0, 0);
  }
}

// 128B rows (BK=64 tiles / flash: 64 bf16 per row).
// LDS[row][slot16] = G[row][slot ^ (row&7)].
__device__ __forceinline__ void stage_rows128(const char* g, long strideB, char* lds,
                                              int nChunks, int tid) {
  const int wave = tid >> 6, lane = tid & 63;
  for (int c = wave; c < nChunks; c += 4) {
    int row = (c << 3) + (lane >> 3);
    int kq = (lane & 7) ^ ((lane >> 3) & 7);
    const char* src = g + (long)row * strideB + kq * 16;
    char* dst = lds + ((long)c << 10);
    __builtin_amdgcn_global_load_lds((const __attribute__((address_space(1))) void*)src,
                                     (__attribute__((address_space(3))) void*)dst,
                                     16, 0, 0);
  }
}

// ---------------------------------------------------------------------------
// NT GEMM, 2-phase prefetch double-buffered LDS (proven path).
// D[m][n] = sum_k A[m][k] * Bw[n][k]  (+ kw-shifted A rows for KW=3)
// BK: 32 (64B rows) or 64 (128B rows; halves barrier-drain events).
// XCD panel swizzle (PY>0): hardware dispatch is round-robin (XCD = gid%8,
// verified by the flash swizzle win in R12). Remap so all blocks of one
// weight panel share gid%8 -> panel fetched from HBM once per XCD, L2-served
// afterwards. R15's contiguous-chunk remap used the WRONG dispatch model.
// Requires GY == 8*PY; bijective by construction.
// EPI: 0 = bf16 [m][ldo] (+bias, relu, maskM opts)
//      2 = QKV split with fused RoPE: n<512 -> O(q), <1024 -> O2(k),
//          else O3 = vT[n-1024][m]
// ---------------------------------------------------------------------------
template <int BM, int BN, int KW, int EPI, bool RELU, bool MASKM, int ZD,
          bool AZL, bool OZL, int MINW, int BK,
          int GX = 0, int GY = 0, int GZ = 0, int PY = 0>
__global__ __launch_bounds__(256, MINW) void gemm_kernel(
    const bf16* __restrict__ A, const bf16* __restrict__ Bw,
    const float* __restrict__ bias, const float* __restrict__ mask,
    bf16* __restrict__ O, bf16* __restrict__ O2, bf16* __restrict__ O3,
    int lda, int ldb, int ldo, int K, long bSlice,
    long aZ1, long aZ2, long bZ1, long bZ2, long oZ1, long oZ2, int zoff,
    const float* __restrict__ ropeC, const float* __restrict__ ropeS)
{
  constexpr int WTM = BM / 2, WTN = BN / 2, FM = WTM / 16, FN = WTN / 16;
  constexpr int RA = (KW == 3) ? BM + 16 : BM;
  constexpr int ROWB = (BK == 64) ? 128 : 64;
  constexpr int ACH = RA * ROWB / 1024;
  constexpr int BCHS = BN * ROWB / 1024;
  constexpr int TCH = ACH + KW * BCHS;
  __shared__ __align__(1024) bf16 sBuf[2][TCH * 512];

  const int tid = threadIdx.x;
  int bx = blockIdx.x, by = blockIdx.y, bz = blockIdx.z;
  if constexpr (PY > 0) {
    constexpr int PBLK = GX * GZ;            // blocks per panel
    static_assert(GY == 8 * PY, "panel swizzle requires GY == 8*PY");
    const int gid = blockIdx.x + GX * (blockIdx.y + GY * blockIdx.z);
    const int xcd = gid & 7;                 // round-robin: XCD = gid % 8
    const int j = gid >> 3;                  // 0 .. NWG/8-1 = PY*PBLK-1
    by = xcd * PY + j / PBLK;                // this XCD owns panels [xcd*PY, ...)
    const int r = j % PBLK;
    bx = r % GX;
    bz = r / GX;
  }
  const int zl = bz, zg = zl + zoff;
  const int zb = zg / ZD, zh = zg % ZD;
  const long aOff = AZL ? (long)zl * aZ1 : (long)zb * aZ1 + (long)zh * aZ2;
  const long bOff = (long)zb * bZ1 + (long)zh * bZ2;
  const long oOff = OZL ? (long)zl * oZ1 : (long)zb * oZ1 + (long)zh * oZ2;
  const int m0 = bx * BM, n0 = by * BN;
  const bf16* Ab = A + aOff + (long)m0 * lda;
  const bf16* Bb = Bw + bOff + (long)n0 * ldb;

  const int wid = tid >> 6, lane = tid & 63;
  const int wm = wid >> 1, wn = wid & 1;
  const int l16 = lane & 15, q4 = lane >> 4;

  f32x4 acc[FM][FN] = {};

  auto STAGE = [&](int k0, int buf) {
    char* sa = (char*)sBuf[buf];
    if constexpr (BK == 64) {
      stage_rows128((const char*)(Ab + k0), (long)lda * 2, sa, ACH, tid);
      #pragma unroll
      for (int kw = 0; kw < KW; ++kw)
        stage_rows128((const char*)(Bb + (long)kw * bSlice + k0), (long)ldb * 2,
                      sa + (ACH + kw * BCHS) * 1024, BCHS, tid);
    } else {
      stage_rows((const char*)(Ab + k0), (long)lda * 2, sa, ACH, tid);
      #pragma unroll
      for (int kw = 0; kw < KW; ++kw)
        stage_rows((const char*)(Bb + (long)kw * bSlice + k0), (long)ldb * 2,
                   sa + (ACH + kw * BCHS) * 1024, BCHS, tid);
    }
  };

  auto COMPUTE = [&](int buf) {
    const char* sa = (const char*)sBuf[buf];
    const char* sb = sa + ACH * 1024;
    if constexpr (BK == 64) {
      #pragma unroll
      for (int kw = 0; kw < KW; ++kw) {
        #pragma unroll
        for (int kk2 = 0; kk2 < 2; ++kk2) {
          bf16x8 af[FM], bfr[FN];
          #pragma unroll
          for (int fm = 0; fm < FM; ++fm) {
            const int row = wm * WTM + fm * 16 + l16 + (KW == 3 ? kw : 0);
            unsigned off = (unsigned)(kk2 * 64 + q4 * 16) ^ ((unsigned)(row & 7) << 4);
            af[fm] = *(const bf16x8*)(sa + row * 128 + off);
          }
          #pragma unroll
          for (int fn = 0; fn < FN; ++fn) {
            const int rn = wn * WTN + fn * 16 + l16;
            unsigned off = (unsigned)(kk2 * 64 + q4 * 16) ^ ((unsigned)(rn & 7) << 4);
            bfr[fn] = *(const bf16x8*)(sb + kw * BCHS * 1024 + rn * 128 + off);
          }
          #pragma unroll
          for (int fm = 0; fm < FM; ++fm)
            #pragma unroll
            for (int fn = 0; fn < FN; ++fn)
              acc[fm][fn] = __builtin_amdgcn_mfma_f32_16x16x32_bf16(af[fm], bfr[fn],
                                                                    acc[fm][fn], 0, 0, 0);
        }
      }
    } else {
      #pragma unroll
      for (int kw = 0; kw < KW; ++kw) {
        bf16x8 af[FM], bfr[FN];
        #pragma unroll
        for (int fm = 0; fm < FM; ++fm) {
          int row = wm * WTM + fm * 16 + l16 + (KW == 3 ? kw : 0);
          unsigned ad = (unsigned)(row * 64 + q4 * 16);
          ad ^= ((ad >> 7) & 3u) << 4;
          af[fm] = *(const bf16x8*)(sa + ad);
        }
        #pragma unroll
        for (int fn = 0; fn < FN; ++fn) {
          int rn = wn * WTN + fn * 16 + l16;
          unsigned bd = (unsigned)(rn * 64 + q4 * 16);
          bd ^= ((bd >> 7) & 3u) << 4;
          bfr[fn] = *(const bf16x8*)(sb + kw * BCHS * 1024 + bd);
        }
        #pragma unroll
        for (int fm = 0; fm < FM; ++fm)
          #pragma unroll
          for (int fn = 0; fn < FN; ++fn)
            acc[fm][fn] = __builtin_amdgcn_mfma_f32_16x16x32_bf16(af[fm], bfr[fn],
                                                                  acc[fm][fn], 0, 0, 0);
      }
    }
  };

  STAGE(0, 0);
  __syncthreads();
  int cur = 0;
  for (int k0 = BK; k0 < K; k0 += BK) {
    STAGE(k0, cur ^ 1);
    COMPUTE(cur);
    __syncthreads();
    cur ^= 1;
  }
  COMPUTE(cur);

  // ---- epilogue: C/D layout col=lane&15, row=(lane>>4)*4+i ----
  float varr[FN][FM][4];
  #pragma unroll
  for (int fn = 0; fn < FN; ++fn) {
    const int nl = n0 + wn * WTN + fn * 16 + l16;
    const float bv = (bias == nullptr) ? 0.f : bias[nl];
    #pragma unroll
    for (int fm = 0; fm < FM; ++fm) {
      const int mb = m0 + wm * WTM + fm * 16 + q4 * 4;
      #pragma unroll
      for (int i = 0; i < 4; ++i) {
        float t = acc[fm][fn][i] + bv;
        if (RELU) t = fmaxf(t, 0.f);
        if (MASKM) t *= mask[(long)zb * T + mb + i];
        varr[fn][fm][i] = t;
      }
    }
  }

  if constexpr (EPI == 2) {
    if (n0 + wn * WTN < 1024) {
      #pragma unroll
      for (int fm = 0; fm < FM; ++fm) {
        const int mb = m0 + wm * WTM + fm * 16 + q4 * 4;
        #pragma unroll
        for (int i = 0; i < 4; ++i) {
          const int t = mb + i;
          float cv = ropeC[t * 16 + l16], sv = ropeS[t * 16 + l16];
          float a = varr[0][fm][i], b2 = varr[1][fm][i];
          varr[0][fm][i] = a * cv - b2 * sv;
          varr[1][fm][i] = b2 * cv + a * sv;
        }
      }
    }
  }

  #pragma unroll
  for (int fn = 0; fn < FN; ++fn) {
    const int nl = n0 + wn * WTN + fn * 16 + l16;
    #pragma unroll
    for (int fm = 0; fm < FM; ++fm) {
      const int mb = m0 + wm * WTM + fm * 16 + q4 * 4;
      if constexpr (EPI == 2) {
        if (nl < 1024) {
          bf16* dst = (nl < 512 ? O : O2) + oOff + (nl & 511);
          #pragma unroll
          for (int i = 0; i < 4; ++i)
            dst[(long)(mb + i) * C] = (bf16)varr[fn][fm][i];
        } else {
          bf16x4v tv;
          #pragma unroll
          for (int i = 0; i < 4; ++i) tv[i] = (bf16)varr[fn][fm][i];
          *(bf16x4v*)(O3 + oOff + (long)(nl - 1024) * T + mb) = tv;
        }
      } else {
        bf16* dst = O + oOff;
        #pragma unroll
        for (int i = 0; i < 4; ++i)
          dst[(long)(mb + i) * ldo + nl] = (bf16)varr[fn][fm][i];
      }
    }
  }
}

// ---------------------------------------------------------------------------
// Flash attention: one block = 64 q-rows x one (b,h). 4 waves x 16 q-rows.
// XCD-aware work swizzle (T1). Fixed-base softmax: p = exp(s - 8).
// ---------------------------------------------------------------------------
__global__ __launch_bounds__(256, 3) void flash_kernel(
    const bf16* __restrict__ q, const bf16* __restrict__ k,
    const bf16* __restrict__ vT, const float* __restrict__ mask,
    bf16* __restrict__ o)
{
  __shared__ __align__(1024) char sQ[64 * 128];
  __shared__ __align__(1024) char sK[2][64 * 128];
  __shared__ __align__(1024) char sV[2][64 * 128];
  __shared__ __align__(1024) char sP[4][16 * 128];

  const int tid = threadIdx.x;
  const int w = tid >> 6, lane = tid & 63;
  const int l16 = lane & 15, q4 = lane >> 4;
  // dispatch-linear id -> XCD-chunked work id (bijective on 512 = 8*64)
  const int g = blockIdx.y * 16 + blockIdx.x;
  const int swz = (g & 7) * 64 + (g >> 3);
  const int q0 = (swz & 15) * 64;
  const int bh = swz >> 4;
  const int b = bh >> 3, h = bh & 7;

  const bf16* qb = q + ((long)b * T + q0) * C + h * 64;
  const bf16* kb = k + (long)b * T * C + h * 64;
  const bf16* vb = vT + (long)b * C * T + (long)h * 64 * T;

  stage_rows128((const char*)qb, (long)C * 2, sQ, 8, tid);
  stage_rows128((const char*)kb, (long)C * 2, sK[0], 8, tid);
  stage_rows128((const char*)vb, (long)T * 2, sV[0], 8, tid);
  __syncthreads();

  bf16x8 af_q[2];
  {
    const int r = w * 16 + l16;
    #pragma unroll
    for (int kk = 0; kk < 2; ++kk) {
      unsigned off = (unsigned)(kk * 64 + q4 * 16) ^ ((unsigned)(r & 7) << 4);
      af_q[kk] = *(const bf16x8*)(sQ + r * 128 + off);
    }
  }

  float mq[4];
  #pragma unroll
  for (int i = 0; i < 4; ++i)
    mq[i] = mask[(long)b * T + q0 + w * 16 + q4 * 4 + i];

  f32x4 accO[4] = {};
  float lrun[4] = {0.f, 0.f, 0.f, 0.f};   // per-lane partial row sums
  char* sPw = sP[w];

  int cur = 0;
  for (int it = 0; it < 16; ++it) {
    if (it < 15) {
      stage_rows128((const char*)(kb + (long)(it + 1) * 64 * C), (long)C * 2, sK[cur ^ 1], 8, tid);
      stage_rows128((const char*)(vb + (it + 1) * 64), (long)T * 2, sV[cur ^ 1], 8, tid);
    }
    f32x4 s[4] = {};
    #pragma unroll
    for (int kk = 0; kk < 2; ++kk) {
      #pragma unroll
      for (int fn = 0; fn < 4; ++fn) {
        const int rn = fn * 16 + l16;
        unsigned off = (unsigned)(kk * 64 + q4 * 16) ^ ((unsigned)(rn & 7) << 4);
        bf16x8 kf = *(const bf16x8*)(sK[cur] + rn * 128 + off);
        s[fn] = __builtin_amdgcn_mfma_f32_16x16x32_bf16(af_q[kk], kf, s[fn], 0, 0, 0);
      }
    }
    float mk[4];
    #pragma unroll
    for (int fn = 0; fn < 4; ++fn)
      mk[fn] = mask[(long)b * T + it * 64 + fn * 16 + l16];
    // fixed-base exp: p = exp(s*SCALE - 8); masked -> exp(-10008) = 0
    #pragma unroll
    for (int fn = 0; fn < 4; ++fn)
      #pragma unroll
      for (int i = 0; i < 4; ++i) {
        float xval = s[fn][i] * SCALE;
        float sv = (mq[i] * mk[fn] > 0.f) ? xval : -10000.f;
        float p = __expf(sv - 8.f);
        lrun[i] += p;
        const int row = q4 * 4 + i;
        unsigned off = (unsigned)((fn * 16 + l16) * 2) ^ ((unsigned)(row & 7) << 4);
        *(bf16*)(sPw + row * 128 + off) = (bf16)p;
      }
    #pragma unroll
    for (int kk = 0; kk < 2; ++kk) {
      unsigned poff = (unsigned)(kk * 64 + q4 * 16) ^ ((unsigned)(l16 & 7) << 4);
      bf16x8 pf = *(const bf16x8*)(sPw + l16 * 128 + poff);
      #pragma unroll
      for (int fn = 0; fn < 4; ++fn) {
        const int rn = fn * 16 + l16;
        unsigned off = (unsigned)(kk * 64 + q4 * 16) ^ ((unsigned)(rn & 7) << 4);
        bf16x8 vf = *(const bf16x8*)(sV[cur] + rn * 128 + off);
        accO[fn] = __builtin_amdgcn_mfma_f32_16x16x32_bf16(pf, vf, accO[fn], 0, 0, 0);
      }
    }
    __syncthreads();
    cur ^= 1;
  }

  // single end-of-loop row-sum reduction over the 16 l16 lanes
  float linv[4];
  #pragma unroll
  for (int i = 0; i < 4; ++i) {
    #pragma unroll
    for (int st = 1; st < 16; st <<= 1) lrun[i] += __shfl_xor(lrun[i], st, 64);
    linv[i] = 1.f / fmaxf(lrun[i], 1e-20f);   // guard fully-masked rows
  }
  #pragma unroll
  for (int fn = 0; fn < 4; ++fn)
    #pragma unroll
    for (int i = 0; i < 4; ++i)
      o[((long)b * T + q0 + w * 16 + q4 * 4 + i) * C + h * 64 + fn * 16 + l16] =
          (bf16)(accO[fn][i] * linv[i]);
}

// ---------------- RoPE table ----------------
__global__ __launch_bounds__(256) void rope_tab_kernel(float* __restrict__ cosT,
                                                       float* __restrict__ sinT) {
  int idx = blockIdx.x * 256 + threadIdx.x;
  if (idx >= T * 16) return;
  int t = idx >> 4, j = idx & 15;
  float theta = powf(10000.f, -(float)j / 16.f);
  float s, c;
  sincosf((float)t * theta, &s, &c);
  cosT[idx] = c;
  sinT[idx] = s;
}

// ---------------- fused residual + LayerNorm over contiguous C ----------------
__global__ __launch_bounds__(256) void ln_kernel(
    const bf16* __restrict__ x, const bf16* __restrict__ y,
    const float* __restrict__ gamma, const float* __restrict__ beta,
    const float* __restrict__ mask, int maskA, int maskY,
    bf16* __restrict__ xout, bf16* __restrict__ xm)
{
  const int w = threadIdx.x >> 6, lane = threadIdx.x & 63;
  const long row = (long)blockIdx.x * 4 + w;
  const int b = (int)(row >> 10), t = (int)(row & 1023);
  const bf16* xr = x + row * C;
  const bf16* yr = y + row * C;
  const float m = mask[(long)b * T + t];
  const float fa = maskA ? m : 1.f, fy = maskY ? m : 1.f;
  bf16x8 xv = *(const bf16x8*)(xr + lane * 8);
  bf16x8 yv = *(const bf16x8*)(yr + lane * 8);
  float vals[8];
  float sum = 0.f, sq = 0.f;
  #pragma unroll
  for (int i = 0; i < 8; ++i) {
    vals[i] = (float)xv[i] * fa + (float)yv[i] * fy;
    sum += vals[i]; sq += vals[i] * vals[i];
  }
  #pragma unroll
  for (int s = 1; s < 64; s <<= 1) {
    sum += __shfl_xor(sum, s, 64);
    sq  += __shfl_xor(sq, s, 64);
  }
  float mean = sum * (1.f / C);
  float rstd = rsqrtf(sq * (1.f / C) - mean * mean + EPS);
  float4 g0 = *(const float4*)(gamma + lane * 8), g1v = *(const float4*)(gamma + lane * 8 + 4);
  float4 b0 = *(const float4*)(beta + lane * 8),  b1v = *(const float4*)(beta + lane * 8 + 4);
  float gg[8] = {g0.x, g0.y, g0.z, g0.w, g1v.x, g1v.y, g1v.z, g1v.w};
  float bb[8] = {b0.x, b0.y, b0.z, b0.w, b1v.x, b1v.y, b1v.z, b1v.w};
  bf16x8 xov, xmv;
  #pragma unroll
  for (int i = 0; i < 8; ++i) {
    float o = (vals[i] - mean) * rstd * gg[i] + bb[i];
    xov[i] = (bf16)o;
    xmv[i] = (bf16)(o * m);
  }
  *(bf16x8*)(xout + row * C + lane * 8) = xov;
  *(bf16x8*)(xm + ((long)b * TP + t + 1) * C + lane * 8) = xmv;
}

// ---------------- transposes [b][C][T] <-> [b][t][C] ----------------
__global__ __launch_bounds__(256) void transpose_in_kernel(const float* __restrict__ xin,
                                                           const float* __restrict__ mask,
                                                           bf16* __restrict__ x,
                                                           bf16* __restrict__ xm) {
  __shared__ float tile[32][33];
  int tx = threadIdx.x, ty = threadIdx.y;
  int t0 = blockIdx.x * 32, c0 = blockIdx.y * 32, b = blockIdx.z;
  #pragma unroll
  for (int i = 0; i < 4; ++i)
    tile[ty + i * 8][tx] = xin[((long)b * C + c0 + ty + i * 8) * T + t0 + tx];
  __syncthreads();
  #pragma unroll
  for (int i = 0; i < 4; ++i) {
    int t = t0 + ty + i * 8;
    float val = tile[tx][ty + i * 8];
    float m = mask[(long)b * T + t];
    x[((long)b * T + t) * C + c0 + tx] = (bf16)val;
    xm[((long)b * TP + t + 1) * C + c0 + tx] = (bf16)(val * m);
  }
}

__global__ __launch_bounds__(256) void transpose_out_kernel(const bf16* __restrict__ x,
                                                            const float* __restrict__ mask,
                                                            float* __restrict__ out) {
  __shared__ float tile[32][33];
  int tx = threadIdx.x, ty = threadIdx.y;
  int t0 = blockIdx.x * 32, c0 = blockIdx.y * 32, b = blockIdx.z;
  #pragma unroll
  for (int i = 0; i < 4; ++i)
    tile[ty + i * 8][tx] = (float)x[((long)b * T + t0 + ty + i * 8) * C + c0 + tx];
  __syncthreads();
  #pragma unroll
  for (int i = 0; i < 4; ++i) {
    int t = t0 + tx;
    out[((long)b * C + c0 + ty + i * 8) * T + t] = tile[tx][ty + i * 8] * mask[(long)b * T + t];
  }
}

// ---------------- zero halo rows of padded activation buffers ----------------
__global__ __launch_bounds__(256) void zero_pads_kernel(bf16* __restrict__ xm, bf16* __restrict__ h) {
  long idx = (long)blockIdx.x * 256 + threadIdx.x;
  const long n1 = (long)B * 18 * C;
  const long n2 = (long)B * 18 * F;
  if (idx < n1) {
    int c = (int)(idx % C); int r = (int)((idx / C) % 18); int b = (int)(idx / (18L * C));
    int p = (r == 0) ? 0 : (T + r);
    xm[((long)b * TP + p) * C + c] = (bf16)0.f;
  } else if (idx < n1 + n2) {
    long j = idx - n1;
    int c = (int)(j % F); int r = (int)((j / F) % 18); int b = (int)(j / (18L * F));
    int p = (r == 0) ? 0 : (T + r);
    h[((long)b * TP + p) * F + c] = (bf16)0.f;
  }
}

// ---------------- one-time all-layer weight conversions ----------------
__global__ __launch_bounds__(256) void cvt_qkv_all(const float* __restrict__ Wq,
                                                   const float* __restrict__ Wk,
                                                   const float* __restrict__ Wv,
                                                   bf16* __restrict__ dst) {
  long idx = (long)blockIdx.x * 256 + threadIdx.x;   // L*3*C*C/4
  if (idx >= (long)L * 3 * C * C / 4) return;
  int c4 = (int)(idx & 127) * 4;
  int n = (int)((idx >> 7) & 511);
  int s2 = (int)(idx >> 16);
  int slot = s2 % 3, i = s2 / 3;
  const float* src = (slot == 0 ? Wq : slot == 1 ? Wk : Wv) + (long)i * C * C + (long)n * C + c4;
  float4 v = *(const float4*)src;
  bf16x4v d = {(bf16)v.x, (bf16)v.y, (bf16)v.z, (bf16)v.w};
  *(bf16x4v*)(dst + (((long)(i * 3 + slot) * 512 + n) * 512 + c4)) = d;
}

__global__ __launch_bounds__(256) void cvt_wo_all(const float* __restrict__ src,
                                                  bf16* __restrict__ dst) {
  long idx = (long)blockIdx.x * 256 + threadIdx.x;   // L*C*C/4
  if (idx >= (long)L * C * C / 4) return;
  float4 v = *(const float4*)(src + idx * 4);
  bf16x4v d = {(bf16)v.x, (bf16)v.y, (bf16)v.z, (bf16)v.w};
  *(bf16x4v*)(dst + idx * 4) = d;
}

// w1/w2: dst[i][k][n][c] = src[i][(n*Kd + c)*3 + k] — coalesced 2-wide.
__global__ __launch_bounds__(256) void cvt_w3_all(const float* __restrict__ src,
                                                  bf16* __restrict__ dst, int N, int Kd) {
  long idx = (long)blockIdx.x * 256 + threadIdx.x;   // L*N*Kd/2
  long total = (long)L * N * Kd / 2;
  if (idx >= total) return;
  const int half = Kd >> 1;
  int c2 = (int)(idx % half) * 2;
  long r = idx / half;
  int n = (int)(r % N);
  int i = (int)(r / N);
  const float* s = src + ((long)i * N * Kd + (long)n * Kd + c2) * 3;
  float v0 = s[0], v1 = s[1], v2 = s[2], v3 = s[3], v4 = s[4], v5 = s[5];
  long plane = (long)N * Kd;
  long baseo = (long)i * 3 * plane + (long)n * Kd + c2;
  bf16x2 d0 = {(bf16)v0, (bf16)v3};
  bf16x2 d1 = {(bf16)v1, (bf16)v4};
  bf16x2 d2 = {(bf16)v2, (bf16)v5};
  *(bf16x2*)(dst + baseo)             = d0;
  *(bf16x2*)(dst + baseo + plane)     = d1;
  *(bf16x2*)(dst + baseo + 2 * plane) = d2;
}

__global__ __launch_bounds__(256) void cvt_bias_all(const float* __restrict__ bq,
                                                    const float* __restrict__ bk,
                                                    const float* __restrict__ bv,
                                                    float* __restrict__ dst) {
  int idx = blockIdx.x * 256 + threadIdx.x;      // L*1536
  if (idx >= L * 1536) return;
  int j = idx % 1536, i = idx / 1536;
  float v = (j < 512) ? bq[i * 512 + j] : (j < 1024) ? bk[i * 512 + j - 512]
                                                     : bv[i * 512 + j - 1024];
  dst[idx] = v;
}

// ---------------------------------------------------------------------------
extern "C" void kernel_launch(void* const* d_in, const int* in_sizes, int n_in,
                              void* d_out, int out_size, void* d_ws, size_t ws_size,
                              hipStream_t stream)
{
  const float* xin = (const float*)d_in[0];
  const float* msk = (const float*)d_in[1];
  const float* Wq  = (const float*)d_in[2];
  const float* bq  = (const float*)d_in[3];
  const float* Wk  = (const float*)d_in[4];
  const float* bk  = (const float*)d_in[5];
  const float* Wv  = (const float*)d_in[6];
  const float* bv  = (const float*)d_in[7];
  const float* Wo  = (const float*)d_in[8];
  const float* bo  = (const float*)d_in[9];
  const float* g1  = (const float*)d_in[10];
  const float* be1 = (const float*)d_in[11];
  const float* W1  = (const float*)d_in[12];
  const float* c1  = (const float*)d_in[13];
  const float* W2  = (const float*)d_in[14];
  const float* c2  = (const float*)d_in[15];
  const float* g2  = (const float*)d_in[16];
  const float* be2 = (const float*)d_in[17];

  size_t off = 0;
  char* base = (char*)d_ws;
  auto alloc = [&](size_t bytes) -> char* {
    char* r = base + off;
    off = (off + bytes + 1023) & ~(size_t)1023;
    return r;
  };
  bf16* x      = (bf16*)alloc((size_t)B * T * C * 2);     // bf16 residual stream
  float* ropeC = (float*)alloc((size_t)T * 16 * 4);
  float* ropeS = (float*)alloc((size_t)T * 16 * 4);
  bf16* xm  = (bf16*)alloc((size_t)B * TP * C * 2);
  bf16* hb  = (bf16*)alloc((size_t)B * TP * F * 2);
  bf16* q   = (bf16*)alloc((size_t)B * T * C * 2);
  bf16* k   = (bf16*)alloc((size_t)B * T * C * 2);
  bf16* vT  = (bf16*)alloc((size_t)B * T * C * 2);
  bf16* o   = (bf16*)alloc((size_t)B * T * C * 2);
  bf16* yb  = (bf16*)alloc((size_t)B * T * C * 2);
  bf16* wqkv_all = (bf16*)alloc((size_t)L * 3 * C * C * 2);
  bf16* wo_all   = (bf16*)alloc((size_t)L * C * C * 2);
  bf16* w1_all   = (bf16*)alloc((size_t)L * 3 * F * C * 2);
  bf16* w2_all   = (bf16*)alloc((size_t)L * 3 * C * F * 2);
  float* bqkv_all = (float*)alloc((size_t)L * 1536 * 4);
  (void)in_sizes; (void)n_in; (void)out_size; (void)ws_size;

  // ---- one-time prologue ----
  {
    long tot = (long)B * 18 * (C + F);
    zero_pads_kernel<<<(int)((tot + 255) / 256), 256, 0, stream>>>(xm, hb);
  }
  transpose_in_kernel<<<dim3(T / 32, C / 32, B), dim3(32, 8), 0, stream>>>(xin, msk, x, xm);
  rope_tab_kernel<<<(T * 16 + 255) / 256, 256, 0, stream>>>(ropeC, ropeS);
  cvt_qkv_all<<<(int)(((long)L * 3 * C * C / 4 + 255) / 256), 256, 0, stream>>>(Wq, Wk, Wv, wqkv_all);
  cvt_wo_all<<<(int)(((long)L * C * C / 4 + 255) / 256), 256, 0, stream>>>(Wo, wo_all);
  cvt_w3_all<<<(int)(((long)L * F * C / 2 + 255) / 256), 256, 0, stream>>>(W1, w1_all, F, C);
  cvt_w3_all<<<(int)(((long)L * C * F / 2 + 255) / 256), 256, 0, stream>>>(W2, w2_all, C, F);
  cvt_bias_all<<<(L * 1536 + 255) / 256, 256, 0, stream>>>(bq, bk, bv, bqkv_all);

  for (int i = 0; i < L; ++i) {
    const bf16* wqkv = wqkv_all + (long)i * 3 * C * C;
    const bf16* wo   = wo_all + (long)i * C * C;
    const bf16* w1b  = w1_all + (long)i * 3 * F * C;
    const bf16* w2b  = w2_all + (long)i * 3 * C * F;
    const float* bqkv = bqkv_all + (long)i * 1536;

    // fused QKV projection (N=1536) + RoPE in epilogue; v stored transposed
    // (12 panels not divisible by 8 XCDs -> no panel swizzle)
    gemm_kernel<64, 128, 1, 2, false, false, 1, false, false, 4, 64>
        <<<dim3(16, 12, B), 256, 0, stream>>>(
        xm + C, wqkv, bqkv, msk, q, k, vT,
        C, C, C, C, 0,
        (long)TP * C, 0, 0, 0, (long)T * C, 0, 0, ropeC, ropeS);

    flash_kernel<<<dim3(T / 64, B * H), 256, 0, stream>>>(q, k, vT, msk, o);

    // O projection (M = B*T) — BK=64, XCD panel swizzle (8 panels, 1/XCD)
    gemm_kernel<64, 64, 1, 0, false, false, 1, false, false, 4, 64,
                64, 8, 1, 1>
        <<<dim3(64, 8, 1), 256, 0, stream>>>(
        o, wo, bo + (size_t)i * C, msk, yb, nullptr, nullptr,
        C, C, C, C, 0,
        0, 0, 0, 0, 0, 0, 0, nullptr, nullptr);

    ln_kernel<<<B * T / 4, 256, 0, stream>>>(x, yb, g1 + (size_t)i * C, be1 + (size_t)i * C,
                                             msk, 1, 0, x, xm);

    // FFN conv1 — 128x128 tile, BK=32, XCD panel swizzle (16 panels, 2/XCD)
    gemm_kernel<128, 128, 3, 0, true, true, 1, false, false, 2, 32,
                8, 16, 4, 2>
        <<<dim3(8, 16, B), 256, 0, stream>>>(
        xm, w1b, c1 + (size_t)i * F, msk, hb + F, nullptr, nullptr,
        C, C, F, C, (long)F * C,
        (long)TP * C, 0, 0, 0, (long)TP * F, 0, 0, nullptr, nullptr);

    // FFN conv2 — 64x64 tile, BK=64, XCD panel swizzle (8 panels, 1/XCD)
    gemm_kernel<64, 64, 3, 0, false, false, 1, false, false, 2, 64,
                16, 8, 4, 1>
        <<<dim3(16, 8, B), 256, 0, stream>>>(
        hb, w2b, c2 + (size_t)i * C, msk, yb, nullptr, nullptr,
        F, F, C, F, (long)C * F,
        (long)TP * F, 0, 0, 0, (long)T * C, 0, 0, nullptr, nullptr);

    ln_kernel<<<B * T / 4, 256, 0, stream>>>(x, yb, g2 + (size_t)i * C, be2 + (size_t)i * C,
                                             msk, 0, 1, x, xm);
  }

  transpose_out_kernel<<<dim3(T / 32, C / 32, B), dim3(32, 8), 0, stream>>>(x, msk, (float*)d_out);
}

// Round 17
// 773.795 us; speedup vs baseline: 1.0168x; 1.0168x over previous
//
#include <hip/hip_runtime.h>

typedef __bf16 bf16;
typedef __bf16 bf16x2 __attribute__((ext_vector_type(2)));
typedef __bf16 bf16x8 __attribute__((ext_vector_type(8)));
typedef __bf16 bf16x4v __attribute__((ext_vector_type(4)));
typedef float f32x4 __attribute__((ext_vector_type(4)));

constexpr int B = 4, C = 512, T = 1024, H = 8, F = 2048, L = 6;
constexpr int TP = T + 18;               // padded rows: row0 = zero, rows T+1..T+17 zero
constexpr float SCALE = 0.125f, EPS = 1e-4f;

// ---------------------------------------------------------------------------
// global -> LDS staging, 64B rows (BK=32 tiles: 32 bf16 k-slice per row)
// LDS linear; swizzle applied on the per-lane GLOBAL source (involution),
// matched by the same XOR on the ds_read side.
// ---------------------------------------------------------------------------
__device__ __forceinline__ void stage_rows(const char* g, long strideB, char* lds,
                                           int nChunks, int tid) {
  const int wave = tid >> 6, lane = tid & 63;
  for (int c = wave; c < nChunks; c += 4) {
    int row = (c << 4) + (lane >> 2);
    int kq = (lane & 3) ^ ((row >> 1) & 3);
    const char* src = g + (long)row * strideB + kq * 16;
    char* dst = lds + ((long)c << 10);
    __builtin_amdgcn_global_load_lds((const __attribute__((address_space(1))) void*)src,
                                     (__attribute__((address_space(3))) void*)dst,
                                     16, 0, 0);
  }
}

// 128B rows (BK=64 tiles / flash: 64 bf16 per row).
// LDS[row][slot16] = G[row][slot ^ (row&7)].
__device__ __forceinline__ void stage_rows128(const char* g, long strideB, char* lds,
                                              int nChunks, int tid) {
  const int wave = tid >> 6, lane = tid & 63;
  for (int c = wave; c < nChunks; c += 4) {
    int row = (c << 3) + (lane >> 3);
    int kq = (lane & 7) ^ ((lane >> 3) & 7);
    const char* src = g + (long)row * strideB + kq * 16;
    char* dst = lds + ((long)c << 10);
    __builtin_amdgcn_global_load_lds((const __attribute__((address_space(1))) void*)src,
                                     (__attribute__((address_space(3))) void*)dst,
                                     16, 0, 0);
  }
}

// ---------------------------------------------------------------------------
// NT GEMM, 2-phase prefetch double-buffered LDS (proven path).
// D[m][n] = sum_k A[m][k] * Bw[n][k]  (+ kw-shifted A rows for KW=3)
// BK: 32 (64B rows) or 64 (128B rows; halves barrier-drain events — proven
//     on FFN2 (R9) and QKV/oproj (R10); NOT at the cost of tile size (R11)).
// Panel swizzles tested R15 (chunk model) & R16 (round-robin model): both
// neutral -> GEMM HBM traffic is not first-order here; reverted.
// EPI: 0 = bf16 [m][ldo] (+bias, relu, maskM opts)
//      2 = QKV split with fused RoPE: n<512 -> O(q), <1024 -> O2(k),
//          else O3 = vT[n-1024][m]
// ---------------------------------------------------------------------------
template <int BM, int BN, int KW, int EPI, bool RELU, bool MASKM, int ZD,
          bool AZL, bool OZL, int MINW, int BK>
__global__ __launch_bounds__(256, MINW) void gemm_kernel(
    const bf16* __restrict__ A, const bf16* __restrict__ Bw,
    const float* __restrict__ bias, const float* __restrict__ mask,
    bf16* __restrict__ O, bf16* __restrict__ O2, bf16* __restrict__ O3,
    int lda, int ldb, int ldo, int K, long bSlice,
    long aZ1, long aZ2, long bZ1, long bZ2, long oZ1, long oZ2, int zoff,
    const float* __restrict__ ropeC, const float* __restrict__ ropeS)
{
  constexpr int WTM = BM / 2, WTN = BN / 2, FM = WTM / 16, FN = WTN / 16;
  constexpr int RA = (KW == 3) ? BM + 16 : BM;
  constexpr int ROWB = (BK == 64) ? 128 : 64;
  constexpr int ACH = RA * ROWB / 1024;
  constexpr int BCHS = BN * ROWB / 1024;
  constexpr int TCH = ACH + KW * BCHS;
  __shared__ __align__(1024) bf16 sBuf[2][TCH * 512];

  const int tid = threadIdx.x;
  const int zl = blockIdx.z, zg = zl + zoff;
  const int zb = zg / ZD, zh = zg % ZD;
  const long aOff = AZL ? (long)zl * aZ1 : (long)zb * aZ1 + (long)zh * aZ2;
  const long bOff = (long)zb * bZ1 + (long)zh * bZ2;
  const long oOff = OZL ? (long)zl * oZ1 : (long)zb * oZ1 + (long)zh * oZ2;
  const int m0 = blockIdx.x * BM, n0 = blockIdx.y * BN;
  const bf16* Ab = A + aOff + (long)m0 * lda;
  const bf16* Bb = Bw + bOff + (long)n0 * ldb;

  const int wid = tid >> 6, lane = tid & 63;
  const int wm = wid >> 1, wn = wid & 1;
  const int l16 = lane & 15, q4 = lane >> 4;

  f32x4 acc[FM][FN] = {};

  auto STAGE = [&](int k0, int buf) {
    char* sa = (char*)sBuf[buf];
    if constexpr (BK == 64) {
      stage_rows128((const char*)(Ab + k0), (long)lda * 2, sa, ACH, tid);
      #pragma unroll
      for (int kw = 0; kw < KW; ++kw)
        stage_rows128((const char*)(Bb + (long)kw * bSlice + k0), (long)ldb * 2,
                      sa + (ACH + kw * BCHS) * 1024, BCHS, tid);
    } else {
      stage_rows((const char*)(Ab + k0), (long)lda * 2, sa, ACH, tid);
      #pragma unroll
      for (int kw = 0; kw < KW; ++kw)
        stage_rows((const char*)(Bb + (long)kw * bSlice + k0), (long)ldb * 2,
                   sa + (ACH + kw * BCHS) * 1024, BCHS, tid);
    }
  };

  auto COMPUTE = [&](int buf) {
    const char* sa = (const char*)sBuf[buf];
    const char* sb = sa + ACH * 1024;
    if constexpr (BK == 64) {
      #pragma unroll
      for (int kw = 0; kw < KW; ++kw) {
        #pragma unroll
        for (int kk2 = 0; kk2 < 2; ++kk2) {
          bf16x8 af[FM], bfr[FN];
          #pragma unroll
          for (int fm = 0; fm < FM; ++fm) {
            const int row = wm * WTM + fm * 16 + l16 + (KW == 3 ? kw : 0);
            unsigned off = (unsigned)(kk2 * 64 + q4 * 16) ^ ((unsigned)(row & 7) << 4);
            af[fm] = *(const bf16x8*)(sa + row * 128 + off);
          }
          #pragma unroll
          for (int fn = 0; fn < FN; ++fn) {
            const int rn = wn * WTN + fn * 16 + l16;
            unsigned off = (unsigned)(kk2 * 64 + q4 * 16) ^ ((unsigned)(rn & 7) << 4);
            bfr[fn] = *(const bf16x8*)(sb + kw * BCHS * 1024 + rn * 128 + off);
          }
          #pragma unroll
          for (int fm = 0; fm < FM; ++fm)
            #pragma unroll
            for (int fn = 0; fn < FN; ++fn)
              acc[fm][fn] = __builtin_amdgcn_mfma_f32_16x16x32_bf16(af[fm], bfr[fn],
                                                                    acc[fm][fn], 0, 0, 0);
        }
      }
    } else {
      #pragma unroll
      for (int kw = 0; kw < KW; ++kw) {
        bf16x8 af[FM], bfr[FN];
        #pragma unroll
        for (int fm = 0; fm < FM; ++fm) {
          int row = wm * WTM + fm * 16 + l16 + (KW == 3 ? kw : 0);
          unsigned ad = (unsigned)(row * 64 + q4 * 16);
          ad ^= ((ad >> 7) & 3u) << 4;
          af[fm] = *(const bf16x8*)(sa + ad);
        }
        #pragma unroll
        for (int fn = 0; fn < FN; ++fn) {
          int rn = wn * WTN + fn * 16 + l16;
          unsigned bd = (unsigned)(rn * 64 + q4 * 16);
          bd ^= ((bd >> 7) & 3u) << 4;
          bfr[fn] = *(const bf16x8*)(sb + kw * BCHS * 1024 + bd);
        }
        #pragma unroll
        for (int fm = 0; fm < FM; ++fm)
          #pragma unroll
          for (int fn = 0; fn < FN; ++fn)
            acc[fm][fn] = __builtin_amdgcn_mfma_f32_16x16x32_bf16(af[fm], bfr[fn],
                                                                  acc[fm][fn], 0, 0, 0);
      }
    }
  };

  STAGE(0, 0);
  __syncthreads();
  int cur = 0;
  for (int k0 = BK; k0 < K; k0 += BK) {
    STAGE(k0, cur ^ 1);
    COMPUTE(cur);
    __syncthreads();
    cur ^= 1;
  }
  COMPUTE(cur);

  // ---- epilogue: C/D layout col=lane&15, row=(lane>>4)*4+i ----
  float varr[FN][FM][4];
  #pragma unroll
  for (int fn = 0; fn < FN; ++fn) {
    const int nl = n0 + wn * WTN + fn * 16 + l16;
    const float bv = (bias == nullptr) ? 0.f : bias[nl];
    #pragma unroll
    for (int fm = 0; fm < FM; ++fm) {
      const int mb = m0 + wm * WTM + fm * 16 + q4 * 4;
      #pragma unroll
      for (int i = 0; i < 4; ++i) {
        float t = acc[fm][fn][i] + bv;
        if (RELU) t = fmaxf(t, 0.f);
        if (MASKM) t *= mask[(long)zb * T + mb + i];
        varr[fn][fm][i] = t;
      }
    }
  }

  if constexpr (EPI == 2) {
    if (n0 + wn * WTN < 1024) {
      #pragma unroll
      for (int fm = 0; fm < FM; ++fm) {
        const int mb = m0 + wm * WTM + fm * 16 + q4 * 4;
        #pragma unroll
        for (int i = 0; i < 4; ++i) {
          const int t = mb + i;
          float cv = ropeC[t * 16 + l16], sv = ropeS[t * 16 + l16];
          float a = varr[0][fm][i], b2 = varr[1][fm][i];
          varr[0][fm][i] = a * cv - b2 * sv;
          varr[1][fm][i] = b2 * cv + a * sv;
        }
      }
    }
  }

  #pragma unroll
  for (int fn = 0; fn < FN; ++fn) {
    const int nl = n0 + wn * WTN + fn * 16 + l16;
    #pragma unroll
    for (int fm = 0; fm < FM; ++fm) {
      const int mb = m0 + wm * WTM + fm * 16 + q4 * 4;
      if constexpr (EPI == 2) {
        if (nl < 1024) {
          bf16* dst = (nl < 512 ? O : O2) + oOff + (nl & 511);
          #pragma unroll
          for (int i = 0; i < 4; ++i)
            dst[(long)(mb + i) * C] = (bf16)varr[fn][fm][i];
        } else {
          bf16x4v tv;
          #pragma unroll
          for (int i = 0; i < 4; ++i) tv[i] = (bf16)varr[fn][fm][i];
          *(bf16x4v*)(O3 + oOff + (long)(nl - 1024) * T + mb) = tv;
        }
      } else {
        bf16* dst = O + oOff;
        #pragma unroll
        for (int i = 0; i < 4; ++i)
          dst[(long)(mb + i) * ldo + nl] = (bf16)varr[fn][fm][i];
      }
    }
  }
}

// ---------------------------------------------------------------------------
// Flash attention: one block = 64 q-rows x one (b,h). 4 waves x 16 q-rows.
// XCD-aware work swizzle (T1). Fixed-base softmax: p = exp(s - 8).
// ---------------------------------------------------------------------------
__global__ __launch_bounds__(256, 3) void flash_kernel(
    const bf16* __restrict__ q, const bf16* __restrict__ k,
    const bf16* __restrict__ vT, const float* __restrict__ mask,
    bf16* __restrict__ o)
{
  __shared__ __align__(1024) char sQ[64 * 128];
  __shared__ __align__(1024) char sK[2][64 * 128];
  __shared__ __align__(1024) char sV[2][64 * 128];
  __shared__ __align__(1024) char sP[4][16 * 128];

  const int tid = threadIdx.x;
  const int w = tid >> 6, lane = tid & 63;
  const int l16 = lane & 15, q4 = lane >> 4;
  // dispatch-linear id -> XCD-chunked work id (bijective on 512 = 8*64)
  const int g = blockIdx.y * 16 + blockIdx.x;
  const int swz = (g & 7) * 64 + (g >> 3);
  const int q0 = (swz & 15) * 64;
  const int bh = swz >> 4;
  const int b = bh >> 3, h = bh & 7;

  const bf16* qb = q + ((long)b * T + q0) * C + h * 64;
  const bf16* kb = k + (long)b * T * C + h * 64;
  const bf16* vb = vT + (long)b * C * T + (long)h * 64 * T;

  stage_rows128((const char*)qb, (long)C * 2, sQ, 8, tid);
  stage_rows128((const char*)kb, (long)C * 2, sK[0], 8, tid);
  stage_rows128((const char*)vb, (long)T * 2, sV[0], 8, tid);
  __syncthreads();

  bf16x8 af_q[2];
  {
    const int r = w * 16 + l16;
    #pragma unroll
    for (int kk = 0; kk < 2; ++kk) {
      unsigned off = (unsigned)(kk * 64 + q4 * 16) ^ ((unsigned)(r & 7) << 4);
      af_q[kk] = *(const bf16x8*)(sQ + r * 128 + off);
    }
  }

  float mq[4];
  #pragma unroll
  for (int i = 0; i < 4; ++i)
    mq[i] = mask[(long)b * T + q0 + w * 16 + q4 * 4 + i];

  f32x4 accO[4] = {};
  float lrun[4] = {0.f, 0.f, 0.f, 0.f};   // per-lane partial row sums
  char* sPw = sP[w];

  int cur = 0;
  for (int it = 0; it < 16; ++it) {
    if (it < 15) {
      stage_rows128((const char*)(kb + (long)(it + 1) * 64 * C), (long)C * 2, sK[cur ^ 1], 8, tid);
      stage_rows128((const char*)(vb + (it + 1) * 64), (long)T * 2, sV[cur ^ 1], 8, tid);
    }
    f32x4 s[4] = {};
    #pragma unroll
    for (int kk = 0; kk < 2; ++kk) {
      #pragma unroll
      for (int fn = 0; fn < 4; ++fn) {
        const int rn = fn * 16 + l16;
        unsigned off = (unsigned)(kk * 64 + q4 * 16) ^ ((unsigned)(rn & 7) << 4);
        bf16x8 kf = *(const bf16x8*)(sK[cur] + rn * 128 + off);
        s[fn] = __builtin_amdgcn_mfma_f32_16x16x32_bf16(af_q[kk], kf, s[fn], 0, 0, 0);
      }
    }
    float mk[4];
    #pragma unroll
    for (int fn = 0; fn < 4; ++fn)
      mk[fn] = mask[(long)b * T + it * 64 + fn * 16 + l16];
    // fixed-base exp: p = exp(s*SCALE - 8); masked -> exp(-10008) = 0
    #pragma unroll
    for (int fn = 0; fn < 4; ++fn)
      #pragma unroll
      for (int i = 0; i < 4; ++i) {
        float xval = s[fn][i] * SCALE;
        float sv = (mq[i] * mk[fn] > 0.f) ? xval : -10000.f;
        float p = __expf(sv - 8.f);
        lrun[i] += p;
        const int row = q4 * 4 + i;
        unsigned off = (unsigned)((fn * 16 + l16) * 2) ^ ((unsigned)(row & 7) << 4);
        *(bf16*)(sPw + row * 128 + off) = (bf16)p;
      }
    #pragma unroll
    for (int kk = 0; kk < 2; ++kk) {
      unsigned poff = (unsigned)(kk * 64 + q4 * 16) ^ ((unsigned)(l16 & 7) << 4);
      bf16x8 pf = *(const bf16x8*)(sPw + l16 * 128 + poff);
      #pragma unroll
      for (int fn = 0; fn < 4; ++fn) {
        const int rn = fn * 16 + l16;
        unsigned off = (unsigned)(kk * 64 + q4 * 16) ^ ((unsigned)(rn & 7) << 4);
        bf16x8 vf = *(const bf16x8*)(sV[cur] + rn * 128 + off);
        accO[fn] = __builtin_amdgcn_mfma_f32_16x16x32_bf16(pf, vf, accO[fn], 0, 0, 0);
      }
    }
    __syncthreads();
    cur ^= 1;
  }

  // single end-of-loop row-sum reduction over the 16 l16 lanes
  float linv[4];
  #pragma unroll
  for (int i = 0; i < 4; ++i) {
    #pragma unroll
    for (int st = 1; st < 16; st <<= 1) lrun[i] += __shfl_xor(lrun[i], st, 64);
    linv[i] = 1.f / fmaxf(lrun[i], 1e-20f);   // guard fully-masked rows
  }
  #pragma unroll
  for (int fn = 0; fn < 4; ++fn)
    #pragma unroll
    for (int i = 0; i < 4; ++i)
      o[((long)b * T + q0 + w * 16 + q4 * 4 + i) * C + h * 64 + fn * 16 + l16] =
          (bf16)(accO[fn][i] * linv[i]);
}

// ---------------- RoPE table ----------------
__global__ __launch_bounds__(256) void rope_tab_kernel(float* __restrict__ cosT,
                                                       float* __restrict__ sinT) {
  int idx = blockIdx.x * 256 + threadIdx.x;
  if (idx >= T * 16) return;
  int t = idx >> 4, j = idx & 15;
  float theta = powf(10000.f, -(float)j / 16.f);
  float s, c;
  sincosf((float)t * theta, &s, &c);
  cosT[idx] = c;
  sinT[idx] = s;
}

// ---------------- fused residual + LayerNorm over contiguous C ----------------
// Residual stream x is bf16 (2% tolerance admits the ~0.2%/layer rounding;
// LN renormalizes each layer so errors don't compound multiplicatively).
__global__ __launch_bounds__(256) void ln_kernel(
    const bf16* __restrict__ x, const bf16* __restrict__ y,
    const float* __restrict__ gamma, const float* __restrict__ beta,
    const float* __restrict__ mask, int maskA, int maskY,
    bf16* __restrict__ xout, bf16* __restrict__ xm)
{
  const int w = threadIdx.x >> 6, lane = threadIdx.x & 63;
  const long row = (long)blockIdx.x * 4 + w;
  const int b = (int)(row >> 10), t = (int)(row & 1023);
  const bf16* xr = x + row * C;
  const bf16* yr = y + row * C;
  const float m = mask[(long)b * T + t];
  const float fa = maskA ? m : 1.f, fy = maskY ? m : 1.f;
  bf16x8 xv = *(const bf16x8*)(xr + lane * 8);
  bf16x8 yv = *(const bf16x8*)(yr + lane * 8);
  float vals[8];
  float sum = 0.f, sq = 0.f;
  #pragma unroll
  for (int i = 0; i < 8; ++i) {
    vals[i] = (float)xv[i] * fa + (float)yv[i] * fy;
    sum += vals[i]; sq += vals[i] * vals[i];
  }
  #pragma unroll
  for (int s = 1; s < 64; s <<= 1) {
    sum += __shfl_xor(sum, s, 64);
    sq  += __shfl_xor(sq, s, 64);
  }
  float mean = sum * (1.f / C);
  float rstd = rsqrtf(sq * (1.f / C) - mean * mean + EPS);
  float4 g0 = *(const float4*)(gamma + lane * 8), g1v = *(const float4*)(gamma + lane * 8 + 4);
  float4 b0 = *(const float4*)(beta + lane * 8),  b1v = *(const float4*)(beta + lane * 8 + 4);
  float gg[8] = {g0.x, g0.y, g0.z, g0.w, g1v.x, g1v.y, g1v.z, g1v.w};
  float bb[8] = {b0.x, b0.y, b0.z, b0.w, b1v.x, b1v.y, b1v.z, b1v.w};
  bf16x8 xov, xmv;
  #pragma unroll
  for (int i = 0; i < 8; ++i) {
    float o = (vals[i] - mean) * rstd * gg[i] + bb[i];
    xov[i] = (bf16)o;
    xmv[i] = (bf16)(o * m);
  }
  *(bf16x8*)(xout + row * C + lane * 8) = xov;
  *(bf16x8*)(xm + ((long)b * TP + t + 1) * C + lane * 8) = xmv;
}

// ---------------- transposes [b][C][T] <-> [b][t][C] ----------------
__global__ __launch_bounds__(256) void transpose_in_kernel(const float* __restrict__ xin,
                                                           const float* __restrict__ mask,
                                                           bf16* __restrict__ x,
                                                           bf16* __restrict__ xm) {
  __shared__ float tile[32][33];
  int tx = threadIdx.x, ty = threadIdx.y;
  int t0 = blockIdx.x * 32, c0 = blockIdx.y * 32, b = blockIdx.z;
  #pragma unroll
  for (int i = 0; i < 4; ++i)
    tile[ty + i * 8][tx] = xin[((long)b * C + c0 + ty + i * 8) * T + t0 + tx];
  __syncthreads();
  #pragma unroll
  for (int i = 0; i < 4; ++i) {
    int t = t0 + ty + i * 8;
    float val = tile[tx][ty + i * 8];
    float m = mask[(long)b * T + t];
    x[((long)b * T + t) * C + c0 + tx] = (bf16)val;
    xm[((long)b * TP + t + 1) * C + c0 + tx] = (bf16)(val * m);
  }
}

__global__ __launch_bounds__(256) void transpose_out_kernel(const bf16* __restrict__ x,
                                                            const float* __restrict__ mask,
                                                            float* __restrict__ out) {
  __shared__ float tile[32][33];
  int tx = threadIdx.x, ty = threadIdx.y;
  int t0 = blockIdx.x * 32, c0 = blockIdx.y * 32, b = blockIdx.z;
  #pragma unroll
  for (int i = 0; i < 4; ++i)
    tile[ty + i * 8][tx] = (float)x[((long)b * T + t0 + ty + i * 8) * C + c0 + tx];
  __syncthreads();
  #pragma unroll
  for (int i = 0; i < 4; ++i) {
    int t = t0 + tx;
    out[((long)b * C + c0 + ty + i * 8) * T + t] = tile[tx][ty + i * 8] * mask[(long)b * T + t];
  }
}

// ---------------- zero halo rows of padded activation buffers ----------------
__global__ __launch_bounds__(256) void zero_pads_kernel(bf16* __restrict__ xm, bf16* __restrict__ h) {
  long idx = (long)blockIdx.x * 256 + threadIdx.x;
  const long n1 = (long)B * 18 * C;
  const long n2 = (long)B * 18 * F;
  if (idx < n1) {
    int c = (int)(idx % C); int r = (int)((idx / C) % 18); int b = (int)(idx / (18L * C));
    int p = (r == 0) ? 0 : (T + r);
    xm[((long)b * TP + p) * C + c] = (bf16)0.f;
  } else if (idx < n1 + n2) {
    long j = idx - n1;
    int c = (int)(j % F); int r = (int)((j / F) % 18); int b = (int)(j / (18L * F));
    int p = (r == 0) ? 0 : (T + r);
    h[((long)b * TP + p) * F + c] = (bf16)0.f;
  }
}

// ---------------- one-time all-layer weight conversions ----------------
__global__ __launch_bounds__(256) void cvt_qkv_all(const float* __restrict__ Wq,
                                                   const float* __restrict__ Wk,
                                                   const float* __restrict__ Wv,
                                                   bf16* __restrict__ dst) {
  long idx = (long)blockIdx.x * 256 + threadIdx.x;   // L*3*C*C/4
  if (idx >= (long)L * 3 * C * C / 4) return;
  int c4 = (int)(idx & 127) * 4;
  int n = (int)((idx >> 7) & 511);
  int s2 = (int)(idx >> 16);
  int slot = s2 % 3, i = s2 / 3;
  const float* src = (slot == 0 ? Wq : slot == 1 ? Wk : Wv) + (long)i * C * C + (long)n * C + c4;
  float4 v = *(const float4*)src;
  bf16x4v d = {(bf16)v.x, (bf16)v.y, (bf16)v.z, (bf16)v.w};
  *(bf16x4v*)(dst + (((long)(i * 3 + slot) * 512 + n) * 512 + c4)) = d;
}

__global__ __launch_bounds__(256) void cvt_wo_all(const float* __restrict__ src,
                                                  bf16* __restrict__ dst) {
  long idx = (long)blockIdx.x * 256 + threadIdx.x;   // L*C*C/4
  if (idx >= (long)L * C * C / 4) return;
  float4 v = *(const float4*)(src + idx * 4);
  bf16x4v d = {(bf16)v.x, (bf16)v.y, (bf16)v.z, (bf16)v.w};
  *(bf16x4v*)(dst + idx * 4) = d;
}

// w1/w2: dst[i][k][n][c] = src[i][(n*Kd + c)*3 + k] — coalesced 2-wide.
__global__ __launch_bounds__(256) void cvt_w3_all(const float* __restrict__ src,
                                                  bf16* __restrict__ dst, int N, int Kd) {
  long idx = (long)blockIdx.x * 256 + threadIdx.x;   // L*N*Kd/2
  long total = (long)L * N * Kd / 2;
  if (idx >= total) return;
  const int half = Kd >> 1;
  int c2 = (int)(idx % half) * 2;
  long r = idx / half;
  int n = (int)(r % N);
  int i = (int)(r / N);
  const float* s = src + ((long)i * N * Kd + (long)n * Kd + c2) * 3;
  float v0 = s[0], v1 = s[1], v2 = s[2], v3 = s[3], v4 = s[4], v5 = s[5];
  long plane = (long)N * Kd;
  long baseo = (long)i * 3 * plane + (long)n * Kd + c2;
  bf16x2 d0 = {(bf16)v0, (bf16)v3};
  bf16x2 d1 = {(bf16)v1, (bf16)v4};
  bf16x2 d2 = {(bf16)v2, (bf16)v5};
  *(bf16x2*)(dst + baseo)             = d0;
  *(bf16x2*)(dst + baseo + plane)     = d1;
  *(bf16x2*)(dst + baseo + 2 * plane) = d2;
}

__global__ __launch_bounds__(256) void cvt_bias_all(const float* __restrict__ bq,
                                                    const float* __restrict__ bk,
                                                    const float* __restrict__ bv,
                                                    float* __restrict__ dst) {
  int idx = blockIdx.x * 256 + threadIdx.x;      // L*1536
  if (idx >= L * 1536) return;
  int j = idx % 1536, i = idx / 1536;
  float v = (j < 512) ? bq[i * 512 + j] : (j < 1024) ? bk[i * 512 + j - 512]
                                                     : bv[i * 512 + j - 1024];
  dst[idx] = v;
}

// ---------------------------------------------------------------------------
extern "C" void kernel_launch(void* const* d_in, const int* in_sizes, int n_in,
                              void* d_out, int out_size, void* d_ws, size_t ws_size,
                              hipStream_t stream)
{
  const float* xin = (const float*)d_in[0];
  const float* msk = (const float*)d_in[1];
  const float* Wq  = (const float*)d_in[2];
  const float* bq  = (const float*)d_in[3];
  const float* Wk  = (const float*)d_in[4];
  const float* bk  = (const float*)d_in[5];
  const float* Wv  = (const float*)d_in[6];
  const float* bv  = (const float*)d_in[7];
  const float* Wo  = (const float*)d_in[8];
  const float* bo  = (const float*)d_in[9];
  const float* g1  = (const float*)d_in[10];
  const float* be1 = (const float*)d_in[11];
  const float* W1  = (const float*)d_in[12];
  const float* c1  = (const float*)d_in[13];
  const float* W2  = (const float*)d_in[14];
  const float* c2  = (const float*)d_in[15];
  const float* g2  = (const float*)d_in[16];
  const float* be2 = (const float*)d_in[17];

  size_t off = 0;
  char* base = (char*)d_ws;
  auto alloc = [&](size_t bytes) -> char* {
    char* r = base + off;
    off = (off + bytes + 1023) & ~(size_t)1023;
    return r;
  };
  bf16* x      = (bf16*)alloc((size_t)B * T * C * 2);     // bf16 residual stream
  float* ropeC = (float*)alloc((size_t)T * 16 * 4);
  float* ropeS = (float*)alloc((size_t)T * 16 * 4);
  bf16* xm  = (bf16*)alloc((size_t)B * TP * C * 2);
  bf16* hb  = (bf16*)alloc((size_t)B * TP * F * 2);
  bf16* q   = (bf16*)alloc((size_t)B * T * C * 2);
  bf16* k   = (bf16*)alloc((size_t)B * T * C * 2);
  bf16* vT  = (bf16*)alloc((size_t)B * T * C * 2);
  bf16* o   = (bf16*)alloc((size_t)B * T * C * 2);
  bf16* yb  = (bf16*)alloc((size_t)B * T * C * 2);
  bf16* wqkv_all = (bf16*)alloc((size_t)L * 3 * C * C * 2);
  bf16* wo_all   = (bf16*)alloc((size_t)L * C * C * 2);
  bf16* w1_all   = (bf16*)alloc((size_t)L * 3 * F * C * 2);
  bf16* w2_all   = (bf16*)alloc((size_t)L * 3 * C * F * 2);
  float* bqkv_all = (float*)alloc((size_t)L * 1536 * 4);
  (void)in_sizes; (void)n_in; (void)out_size; (void)ws_size;

  // ---- one-time prologue ----
  {
    long tot = (long)B * 18 * (C + F);
    zero_pads_kernel<<<(int)((tot + 255) / 256), 256, 0, stream>>>(xm, hb);
  }
  transpose_in_kernel<<<dim3(T / 32, C / 32, B), dim3(32, 8), 0, stream>>>(xin, msk, x, xm);
  rope_tab_kernel<<<(T * 16 + 255) / 256, 256, 0, stream>>>(ropeC, ropeS);
  cvt_qkv_all<<<(int)(((long)L * 3 * C * C / 4 + 255) / 256), 256, 0, stream>>>(Wq, Wk, Wv, wqkv_all);
  cvt_wo_all<<<(int)(((long)L * C * C / 4 + 255) / 256), 256, 0, stream>>>(Wo, wo_all);
  cvt_w3_all<<<(int)(((long)L * F * C / 2 + 255) / 256), 256, 0, stream>>>(W1, w1_all, F, C);
  cvt_w3_all<<<(int)(((long)L * C * F / 2 + 255) / 256), 256, 0, stream>>>(W2, w2_all, C, F);
  cvt_bias_all<<<(L * 1536 + 255) / 256, 256, 0, stream>>>(bq, bk, bv, bqkv_all);

  for (int i = 0; i < L; ++i) {
    const bf16* wqkv = wqkv_all + (long)i * 3 * C * C;
    const bf16* wo   = wo_all + (long)i * C * C;
    const bf16* w1b  = w1_all + (long)i * 3 * F * C;
    const bf16* w2b  = w2_all + (long)i * 3 * C * F;
    const float* bqkv = bqkv_all + (long)i * 1536;

    // fused QKV projection (N=1536) + RoPE in epilogue; v stored transposed
    gemm_kernel<64, 128, 1, 2, false, false, 1, false, false, 4, 64>
        <<<dim3(16, 12, B), 256, 0, stream>>>(
        xm + C, wqkv, bqkv, msk, q, k, vT,
        C, C, C, C, 0,
        (long)TP * C, 0, 0, 0, (long)T * C, 0, 0, ropeC, ropeS);

    flash_kernel<<<dim3(T / 64, B * H), 256, 0, stream>>>(q, k, vT, msk, o);

    // O projection (batch flattened: M = B*T) — BK=64
    gemm_kernel<64, 64, 1, 0, false, false, 1, false, false, 4, 64>
        <<<dim3(64, 8, 1), 256, 0, stream>>>(
        o, wo, bo + (size_t)i * C, msk, yb, nullptr, nullptr,
        C, C, C, C, 0,
        0, 0, 0, 0, 0, 0, 0, nullptr, nullptr);

    ln_kernel<<<B * T / 4, 256, 0, stream>>>(x, yb, g1 + (size_t)i * C, be1 + (size_t)i * C,
                                             msk, 1, 0, x, xm);

    // FFN conv1 (K=3, relu, masked output) — 128x128 tile, BK=32 (R10-proven)
    gemm_kernel<128, 128, 3, 0, true, true, 1, false, false, 2, 32>
        <<<dim3(8, 16, B), 256, 0, stream>>>(
        xm, w1b, c1 + (size_t)i * F, msk, hb + F, nullptr, nullptr,
        C, C, F, C, (long)F * C,
        (long)TP * C, 0, 0, 0, (long)TP * F, 0, 0, nullptr, nullptr);

    // FFN conv2 (K=3) — 64x64 tile, BK=64
    gemm_kernel<64, 64, 3, 0, false, false, 1, false, false, 2, 64>
        <<<dim3(16, 8, B), 256, 0, stream>>>(
        hb, w2b, c2 + (size_t)i * C, msk, yb, nullptr, nullptr,
        F, F, C, F, (long)C * F,
        (long)TP * F, 0, 0, 0, (long)T * C, 0, 0, nullptr, nullptr);

    ln_kernel<<<B * T / 4, 256, 0, stream>>>(x, yb, g2 + (size_t)i * C, be2 + (size_t)i * C,
                                             msk, 0, 1, x, xm);
  }

  transpose_out_kernel<<<dim3(T / 32, C / 32, B), dim3(32, 8), 0, stream>>>(x, msk, (float*)d_out);
}

// Round 18
// 764.548 us; speedup vs baseline: 1.0291x; 1.0121x over previous
//
#include <hip/hip_runtime.h>

typedef __bf16 bf16;
typedef __bf16 bf16x2 __attribute__((ext_vector_type(2)));
typedef __bf16 bf16x8 __attribute__((ext_vector_type(8)));
typedef __bf16 bf16x4v __attribute__((ext_vector_type(4)));
typedef float f32x4 __attribute__((ext_vector_type(4)));

constexpr int B = 4, C = 512, T = 1024, H = 8, F = 2048, L = 6;
constexpr int TP = T + 18;               // padded rows: row0 = zero, rows T+1..T+17 zero
constexpr float SCALE = 0.125f, EPS = 1e-4f;

// ---------------------------------------------------------------------------
// global -> LDS staging, 64B rows (BK=32 tiles: 32 bf16 k-slice per row)
// LDS linear; swizzle applied on the per-lane GLOBAL source (involution),
// matched by the same XOR on the ds_read side.
// ---------------------------------------------------------------------------
__device__ __forceinline__ void stage_rows(const char* g, long strideB, char* lds,
                                           int nChunks, int tid) {
  const int wave = tid >> 6, lane = tid & 63;
  for (int c = wave; c < nChunks; c += 4) {
    int row = (c << 4) + (lane >> 2);
    int kq = (lane & 3) ^ ((row >> 1) & 3);
    const char* src = g + (long)row * strideB + kq * 16;
    char* dst = lds + ((long)c << 10);
    __builtin_amdgcn_global_load_lds((const __attribute__((address_space(1))) void*)src,
                                     (__attribute__((address_space(3))) void*)dst,
                                     16, 0, 0);
  }
}

// 128B rows (BK=64 tiles / flash: 64 bf16 per row).
// LDS[row][slot16] = G[row][slot ^ (row&7)].
__device__ __forceinline__ void stage_rows128(const char* g, long strideB, char* lds,
                                              int nChunks, int tid) {
  const int wave = tid >> 6, lane = tid & 63;
  for (int c = wave; c < nChunks; c += 4) {
    int row = (c << 3) + (lane >> 3);
    int kq = (lane & 7) ^ ((lane >> 3) & 7);
    const char* src = g + (long)row * strideB + kq * 16;
    char* dst = lds + ((long)c << 10);
    __builtin_amdgcn_global_load_lds((const __attribute__((address_space(1))) void*)src,
                                     (__attribute__((address_space(3))) void*)dst,
                                     16, 0, 0);
  }
}

// ---------------------------------------------------------------------------
// NT GEMM, 2-phase prefetch double-buffered LDS (proven path).
// D[m][n] = sum_k A[m][k] * Bw[n][k]  (+ kw-shifted A rows for KW=3)
// BK: 32 (64B rows) or 64 (128B rows; halves barrier-drain events — proven
//     on FFN2 (R9) and QKV/oproj (R10); NOT at the cost of tile size (R11)).
// EPI: 0 = bf16 [m][ldo] (+bias, relu, maskM opts)
//      2 = QKV split with fused RoPE: n<512 -> O(q), <1024 -> O2(k),
//          else O3 = vT[n-1024][m]
// ---------------------------------------------------------------------------
template <int BM, int BN, int KW, int EPI, bool RELU, bool MASKM, int ZD,
          bool AZL, bool OZL, int MINW, int BK>
__global__ __launch_bounds__(256, MINW) void gemm_kernel(
    const bf16* __restrict__ A, const bf16* __restrict__ Bw,
    const float* __restrict__ bias, const float* __restrict__ mask,
    bf16* __restrict__ O, bf16* __restrict__ O2, bf16* __restrict__ O3,
    int lda, int ldb, int ldo, int K, long bSlice,
    long aZ1, long aZ2, long bZ1, long bZ2, long oZ1, long oZ2, int zoff,
    const float* __restrict__ ropeC, const float* __restrict__ ropeS)
{
  constexpr int WTM = BM / 2, WTN = BN / 2, FM = WTM / 16, FN = WTN / 16;
  constexpr int RA = (KW == 3) ? BM + 16 : BM;
  constexpr int ROWB = (BK == 64) ? 128 : 64;
  constexpr int ACH = RA * ROWB / 1024;
  constexpr int BCHS = BN * ROWB / 1024;
  constexpr int TCH = ACH + KW * BCHS;
  __shared__ __align__(1024) bf16 sBuf[2][TCH * 512];

  const int tid = threadIdx.x;
  const int zl = blockIdx.z, zg = zl + zoff;
  const int zb = zg / ZD, zh = zg % ZD;
  const long aOff = AZL ? (long)zl * aZ1 : (long)zb * aZ1 + (long)zh * aZ2;
  const long bOff = (long)zb * bZ1 + (long)zh * bZ2;
  const long oOff = OZL ? (long)zl * oZ1 : (long)zb * oZ1 + (long)zh * oZ2;
  const int m0 = blockIdx.x * BM, n0 = blockIdx.y * BN;
  const bf16* Ab = A + aOff + (long)m0 * lda;
  const bf16* Bb = Bw + bOff + (long)n0 * ldb;

  const int wid = tid >> 6, lane = tid & 63;
  const int wm = wid >> 1, wn = wid & 1;
  const int l16 = lane & 15, q4 = lane >> 4;

  f32x4 acc[FM][FN] = {};

  auto STAGE = [&](int k0, int buf) {
    char* sa = (char*)sBuf[buf];
    if constexpr (BK == 64) {
      stage_rows128((const char*)(Ab + k0), (long)lda * 2, sa, ACH, tid);
      #pragma unroll
      for (int kw = 0; kw < KW; ++kw)
        stage_rows128((const char*)(Bb + (long)kw * bSlice + k0), (long)ldb * 2,
                      sa + (ACH + kw * BCHS) * 1024, BCHS, tid);
    } else {
      stage_rows((const char*)(Ab + k0), (long)lda * 2, sa, ACH, tid);
      #pragma unroll
      for (int kw = 0; kw < KW; ++kw)
        stage_rows((const char*)(Bb + (long)kw * bSlice + k0), (long)ldb * 2,
                   sa + (ACH + kw * BCHS) * 1024, BCHS, tid);
    }
  };

  auto COMPUTE = [&](int buf) {
    const char* sa = (const char*)sBuf[buf];
    const char* sb = sa + ACH * 1024;
    if constexpr (BK == 64) {
      #pragma unroll
      for (int kw = 0; kw < KW; ++kw) {
        #pragma unroll
        for (int kk2 = 0; kk2 < 2; ++kk2) {
          bf16x8 af[FM], bfr[FN];
          #pragma unroll
          for (int fm = 0; fm < FM; ++fm) {
            const int row = wm * WTM + fm * 16 + l16 + (KW == 3 ? kw : 0);
            unsigned off = (unsigned)(kk2 * 64 + q4 * 16) ^ ((unsigned)(row & 7) << 4);
            af[fm] = *(const bf16x8*)(sa + row * 128 + off);
          }
          #pragma unroll
          for (int fn = 0; fn < FN; ++fn) {
            const int rn = wn * WTN + fn * 16 + l16;
            unsigned off = (unsigned)(kk2 * 64 + q4 * 16) ^ ((unsigned)(rn & 7) << 4);
            bfr[fn] = *(const bf16x8*)(sb + kw * BCHS * 1024 + rn * 128 + off);
          }
          #pragma unroll
          for (int fm = 0; fm < FM; ++fm)
            #pragma unroll
            for (int fn = 0; fn < FN; ++fn)
              acc[fm][fn] = __builtin_amdgcn_mfma_f32_16x16x32_bf16(af[fm], bfr[fn],
                                                                    acc[fm][fn], 0, 0, 0);
        }
      }
    } else {
      #pragma unroll
      for (int kw = 0; kw < KW; ++kw) {
        bf16x8 af[FM], bfr[FN];
        #pragma unroll
        for (int fm = 0; fm < FM; ++fm) {
          int row = wm * WTM + fm * 16 + l16 + (KW == 3 ? kw : 0);
          unsigned ad = (unsigned)(row * 64 + q4 * 16);
          ad ^= ((ad >> 7) & 3u) << 4;
          af[fm] = *(const bf16x8*)(sa + ad);
        }
        #pragma unroll
        for (int fn = 0; fn < FN; ++fn) {
          int rn = wn * WTN + fn * 16 + l16;
          unsigned bd = (unsigned)(rn * 64 + q4 * 16);
          bd ^= ((bd >> 7) & 3u) << 4;
          bfr[fn] = *(const bf16x8*)(sb + kw * BCHS * 1024 + bd);
        }
        #pragma unroll
        for (int fm = 0; fm < FM; ++fm)
          #pragma unroll
          for (int fn = 0; fn < FN; ++fn)
            acc[fm][fn] = __builtin_amdgcn_mfma_f32_16x16x32_bf16(af[fm], bfr[fn],
                                                                  acc[fm][fn], 0, 0, 0);
      }
    }
  };

  STAGE(0, 0);
  __syncthreads();
  int cur = 0;
  for (int k0 = BK; k0 < K; k0 += BK) {
    STAGE(k0, cur ^ 1);
    COMPUTE(cur);
    __syncthreads();
    cur ^= 1;
  }
  COMPUTE(cur);

  // ---- epilogue: C/D layout col=lane&15, row=(lane>>4)*4+i ----
  float varr[FN][FM][4];
  #pragma unroll
  for (int fn = 0; fn < FN; ++fn) {
    const int nl = n0 + wn * WTN + fn * 16 + l16;
    const float bv = (bias == nullptr) ? 0.f : bias[nl];
    #pragma unroll
    for (int fm = 0; fm < FM; ++fm) {
      const int mb = m0 + wm * WTM + fm * 16 + q4 * 4;
      #pragma unroll
      for (int i = 0; i < 4; ++i) {
        float t = acc[fm][fn][i] + bv;
        if (RELU) t = fmaxf(t, 0.f);
        if (MASKM) t *= mask[(long)zb * T + mb + i];
        varr[fn][fm][i] = t;
      }
    }
  }

  if constexpr (EPI == 2) {
    if (n0 + wn * WTN < 1024) {
      #pragma unroll
      for (int fm = 0; fm < FM; ++fm) {
        const int mb = m0 + wm * WTM + fm * 16 + q4 * 4;
        #pragma unroll
        for (int i = 0; i < 4; ++i) {
          const int t = mb + i;
          float cv = ropeC[t * 16 + l16], sv = ropeS[t * 16 + l16];
          float a = varr[0][fm][i], b2 = varr[1][fm][i];
          varr[0][fm][i] = a * cv - b2 * sv;
          varr[1][fm][i] = b2 * cv + a * sv;
        }
      }
    }
  }

  #pragma unroll
  for (int fn = 0; fn < FN; ++fn) {
    const int nl = n0 + wn * WTN + fn * 16 + l16;
    #pragma unroll
    for (int fm = 0; fm < FM; ++fm) {
      const int mb = m0 + wm * WTM + fm * 16 + q4 * 4;
      if constexpr (EPI == 2) {
        if (nl < 1024) {
          bf16* dst = (nl < 512 ? O : O2) + oOff + (nl & 511);
          #pragma unroll
          for (int i = 0; i < 4; ++i)
            dst[(long)(mb + i) * C] = (bf16)varr[fn][fm][i];
        } else {
          bf16x4v tv;
          #pragma unroll
          for (int i = 0; i < 4; ++i) tv[i] = (bf16)varr[fn][fm][i];
          *(bf16x4v*)(O3 + oOff + (long)(nl - 1024) * T + mb) = tv;
        }
      } else {
        bf16* dst = O + oOff;
        #pragma unroll
        for (int i = 0; i < 4; ++i)
          dst[(long)(mb + i) * ldo + nl] = (bf16)varr[fn][fm][i];
      }
    }
  }
}

// ---------------------------------------------------------------------------
// Flash attention: one block = 64 q-rows x one (b,h). 4 waves x 16 q-rows.
// XCD-aware work swizzle (T1). Fixed-base softmax: p = exp(s - 8).
// ---------------------------------------------------------------------------
__global__ __launch_bounds__(256, 3) void flash_kernel(
    const bf16* __restrict__ q, const bf16* __restrict__ k,
    const bf16* __restrict__ vT, const float* __restrict__ mask,
    bf16* __restrict__ o)
{
  __shared__ __align__(1024) char sQ[64 * 128];
  __shared__ __align__(1024) char sK[2][64 * 128];
  __shared__ __align__(1024) char sV[2][64 * 128];
  __shared__ __align__(1024) char sP[4][16 * 128];

  const int tid = threadIdx.x;
  const int w = tid >> 6, lane = tid & 63;
  const int l16 = lane & 15, q4 = lane >> 4;
  // dispatch-linear id -> XCD-chunked work id (bijective on 512 = 8*64)
  const int g = blockIdx.y * 16 + blockIdx.x;
  const int swz = (g & 7) * 64 + (g >> 3);
  const int q0 = (swz & 15) * 64;
  const int bh = swz >> 4;
  const int b = bh >> 3, h = bh & 7;

  const bf16* qb = q + ((long)b * T + q0) * C + h * 64;
  const bf16* kb = k + (long)b * T * C + h * 64;
  const bf16* vb = vT + (long)b * C * T + (long)h * 64 * T;

  stage_rows128((const char*)qb, (long)C * 2, sQ, 8, tid);
  stage_rows128((const char*)kb, (long)C * 2, sK[0], 8, tid);
  stage_rows128((const char*)vb, (long)T * 2, sV[0], 8, tid);
  __syncthreads();

  bf16x8 af_q[2];
  {
    const int r = w * 16 + l16;
    #pragma unroll
    for (int kk = 0; kk < 2; ++kk) {
      unsigned off = (unsigned)(kk * 64 + q4 * 16) ^ ((unsigned)(r & 7) << 4);
      af_q[kk] = *(const bf16x8*)(sQ + r * 128 + off);
    }
  }

  float mq[4];
  #pragma unroll
  for (int i = 0; i < 4; ++i)
    mq[i] = mask[(long)b * T + q0 + w * 16 + q4 * 4 + i];

  f32x4 accO[4] = {};
  float lrun[4] = {0.f, 0.f, 0.f, 0.f};   // per-lane partial row sums
  char* sPw = sP[w];

  int cur = 0;
  for (int it = 0; it < 16; ++it) {
    if (it < 15) {
      stage_rows128((const char*)(kb + (long)(it + 1) * 64 * C), (long)C * 2, sK[cur ^ 1], 8, tid);
      stage_rows128((const char*)(vb + (it + 1) * 64), (long)T * 2, sV[cur ^ 1], 8, tid);
    }
    f32x4 s[4] = {};
    #pragma unroll
    for (int kk = 0; kk < 2; ++kk) {
      #pragma unroll
      for (int fn = 0; fn < 4; ++fn) {
        const int rn = fn * 16 + l16;
        unsigned off = (unsigned)(kk * 64 + q4 * 16) ^ ((unsigned)(rn & 7) << 4);
        bf16x8 kf = *(const bf16x8*)(sK[cur] + rn * 128 + off);
        s[fn] = __builtin_amdgcn_mfma_f32_16x16x32_bf16(af_q[kk], kf, s[fn], 0, 0, 0);
      }
    }
    float mk[4];
    #pragma unroll
    for (int fn = 0; fn < 4; ++fn)
      mk[fn] = mask[(long)b * T + it * 64 + fn * 16 + l16];
    // fixed-base exp: p = exp(s*SCALE - 8); masked -> exp(-10008) = 0
    #pragma unroll
    for (int fn = 0; fn < 4; ++fn)
      #pragma unroll
      for (int i = 0; i < 4; ++i) {
        float xval = s[fn][i] * SCALE;
        float sv = (mq[i] * mk[fn] > 0.f) ? xval : -10000.f;
        float p = __expf(sv - 8.f);
        lrun[i] += p;
        const int row = q4 * 4 + i;
        unsigned off = (unsigned)((fn * 16 + l16) * 2) ^ ((unsigned)(row & 7) << 4);
        *(bf16*)(sPw + row * 128 + off) = (bf16)p;
      }
    #pragma unroll
    for (int kk = 0; kk < 2; ++kk) {
      unsigned poff = (unsigned)(kk * 64 + q4 * 16) ^ ((unsigned)(l16 & 7) << 4);
      bf16x8 pf = *(const bf16x8*)(sPw + l16 * 128 + poff);
      #pragma unroll
      for (int fn = 0; fn < 4; ++fn) {
        const int rn = fn * 16 + l16;
        unsigned off = (unsigned)(kk * 64 + q4 * 16) ^ ((unsigned)(rn & 7) << 4);
        bf16x8 vf = *(const bf16x8*)(sV[cur] + rn * 128 + off);
        accO[fn] = __builtin_amdgcn_mfma_f32_16x16x32_bf16(pf, vf, accO[fn], 0, 0, 0);
      }
    }
    __syncthreads();
    cur ^= 1;
  }

  // single end-of-loop row-sum reduction over the 16 l16 lanes
  float linv[4];
  #pragma unroll
  for (int i = 0; i < 4; ++i) {
    #pragma unroll
    for (int st = 1; st < 16; st <<= 1) lrun[i] += __shfl_xor(lrun[i], st, 64);
    linv[i] = 1.f / fmaxf(lrun[i], 1e-20f);   // guard fully-masked rows
  }
  #pragma unroll
  for (int fn = 0; fn < 4; ++fn)
    #pragma unroll
    for (int i = 0; i < 4; ++i)
      o[((long)b * T + q0 + w * 16 + q4 * 4 + i) * C + h * 64 + fn * 16 + l16] =
          (bf16)(accO[fn][i] * linv[i]);
}

// ---------------- fused residual + LayerNorm over contiguous C ----------------
// Residual stream x is bf16 (2% tolerance admits the ~0.2%/layer rounding;
// LN renormalizes each layer so errors don't compound multiplicatively).
__global__ __launch_bounds__(256) void ln_kernel(
    const bf16* __restrict__ x, const bf16* __restrict__ y,
    const float* __restrict__ gamma, const float* __restrict__ beta,
    const float* __restrict__ mask, int maskA, int maskY,
    bf16* __restrict__ xout, bf16* __restrict__ xm)
{
  const int w = threadIdx.x >> 6, lane = threadIdx.x & 63;
  const long row = (long)blockIdx.x * 4 + w;
  const int b = (int)(row >> 10), t = (int)(row & 1023);
  const bf16* xr = x + row * C;
  const bf16* yr = y + row * C;
  const float m = mask[(long)b * T + t];
  const float fa = maskA ? m : 1.f, fy = maskY ? m : 1.f;
  bf16x8 xv = *(const bf16x8*)(xr + lane * 8);
  bf16x8 yv = *(const bf16x8*)(yr + lane * 8);
  float vals[8];
  float sum = 0.f, sq = 0.f;
  #pragma unroll
  for (int i = 0; i < 8; ++i) {
    vals[i] = (float)xv[i] * fa + (float)yv[i] * fy;
    sum += vals[i]; sq += vals[i] * vals[i];
  }
  #pragma unroll
  for (int s = 1; s < 64; s <<= 1) {
    sum += __shfl_xor(sum, s, 64);
    sq  += __shfl_xor(sq, s, 64);
  }
  float mean = sum * (1.f / C);
  float rstd = rsqrtf(sq * (1.f / C) - mean * mean + EPS);
  float4 g0 = *(const float4*)(gamma + lane * 8), g1v = *(const float4*)(gamma + lane * 8 + 4);
  float4 b0 = *(const float4*)(beta + lane * 8),  b1v = *(const float4*)(beta + lane * 8 + 4);
  float gg[8] = {g0.x, g0.y, g0.z, g0.w, g1v.x, g1v.y, g1v.z, g1v.w};
  float bb[8] = {b0.x, b0.y, b0.z, b0.w, b1v.x, b1v.y, b1v.z, b1v.w};
  bf16x8 xov, xmv;
  #pragma unroll
  for (int i = 0; i < 8; ++i) {
    float o = (vals[i] - mean) * rstd * gg[i] + bb[i];
    xov[i] = (bf16)o;
    xmv[i] = (bf16)(o * m);
  }
  *(bf16x8*)(xout + row * C + lane * 8) = xov;
  *(bf16x8*)(xm + ((long)b * TP + t + 1) * C + lane * 8) = xmv;
}

// ---------------- transposes [b][C][T] <-> [b][t][C] ----------------
__global__ __launch_bounds__(256) void transpose_in_kernel(const float* __restrict__ xin,
                                                           const float* __restrict__ mask,
                                                           bf16* __restrict__ x,
                                                           bf16* __restrict__ xm) {
  __shared__ float tile[32][33];
  int tx = threadIdx.x, ty = threadIdx.y;
  int t0 = blockIdx.x * 32, c0 = blockIdx.y * 32, b = blockIdx.z;
  #pragma unroll
  for (int i = 0; i < 4; ++i)
    tile[ty + i * 8][tx] = xin[((long)b * C + c0 + ty + i * 8) * T + t0 + tx];
  __syncthreads();
  #pragma unroll
  for (int i = 0; i < 4; ++i) {
    int t = t0 + ty + i * 8;
    float val = tile[tx][ty + i * 8];
    float m = mask[(long)b * T + t];
    x[((long)b * T + t) * C + c0 + tx] = (bf16)val;
    xm[((long)b * TP + t + 1) * C + c0 + tx] = (bf16)(val * m);
  }
}

__global__ __launch_bounds__(256) void transpose_out_kernel(const bf16* __restrict__ x,
                                                            const float* __restrict__ mask,
                                                            float* __restrict__ out) {
  __shared__ float tile[32][33];
  int tx = threadIdx.x, ty = threadIdx.y;
  int t0 = blockIdx.x * 32, c0 = blockIdx.y * 32, b = blockIdx.z;
  #pragma unroll
  for (int i = 0; i < 4; ++i)
    tile[ty + i * 8][tx] = (float)x[((long)b * T + t0 + ty + i * 8) * C + c0 + tx];
  __syncthreads();
  #pragma unroll
  for (int i = 0; i < 4; ++i) {
    int t = t0 + tx;
    out[((long)b * C + c0 + ty + i * 8) * T + t] = tile[tx][ty + i * 8] * mask[(long)b * T + t];
  }
}

// ---------------------------------------------------------------------------
// Merged prologue misc: zero halo pads + RoPE table + bias concat (one grid,
// index-range dispatch; logic identical to the three former kernels).
// ---------------------------------------------------------------------------
__global__ __launch_bounds__(256) void prologue_misc_kernel(
    bf16* __restrict__ xm, bf16* __restrict__ hb,
    float* __restrict__ cosT, float* __restrict__ sinT,
    const float* __restrict__ bq, const float* __restrict__ bk,
    const float* __restrict__ bv, float* __restrict__ bqkv_all)
{
  const long n1 = (long)B * 18 * C;
  const long n2 = (long)B * 18 * F;
  const long nR = (long)T * 16;
  const long nB = (long)L * 1536;
  long idx = (long)blockIdx.x * 256 + threadIdx.x;
  if (idx < n1) {
    int c = (int)(idx % C); int r = (int)((idx / C) % 18); int b = (int)(idx / (18L * C));
    int p = (r == 0) ? 0 : (T + r);
    xm[((long)b * TP + p) * C + c] = (bf16)0.f;
  } else if (idx < n1 + n2) {
    long j = idx - n1;
    int c = (int)(j % F); int r = (int)((j / F) % 18); int b = (int)(j / (18L * F));
    int p = (r == 0) ? 0 : (T + r);
    hb[((long)b * TP + p) * F + c] = (bf16)0.f;
  } else if (idx < n1 + n2 + nR) {
    long j = idx - n1 - n2;
    int t = (int)(j >> 4), jj = (int)(j & 15);
    float theta = powf(10000.f, -(float)jj / 16.f);
    float s, c;
    sincosf((float)t * theta, &s, &c);
    cosT[j] = c;
    sinT[j] = s;
  } else if (idx < n1 + n2 + nR + nB) {
    long j2 = idx - n1 - n2 - nR;
    int j = (int)(j2 % 1536), i = (int)(j2 / 1536);
    float v = (j < 512) ? bq[i * 512 + j] : (j < 1024) ? bk[i * 512 + j - 512]
                                                       : bv[i * 512 + j - 1024];
    bqkv_all[j2] = v;
  }
}

// ---------------------------------------------------------------------------
// Merged square-weight conversion: qkv (interleaved [i][slot][n][c]) + wo.
// ---------------------------------------------------------------------------
__global__ __launch_bounds__(256) void cvt_qkvo_kernel(
    const float* __restrict__ Wq, const float* __restrict__ Wk,
    const float* __restrict__ Wv, const float* __restrict__ Wo,
    bf16* __restrict__ wqkv_all, bf16* __restrict__ wo_all)
{
  const long nQ = (long)L * 3 * C * C / 4;
  const long nO = (long)L * C * C / 4;
  long idx = (long)blockIdx.x * 256 + threadIdx.x;
  if (idx < nQ) {
    int c4 = (int)(idx & 127) * 4;
    int n = (int)((idx >> 7) & 511);
    int s2 = (int)(idx >> 16);
    int slot = s2 % 3, i = s2 / 3;
    const float* src = (slot == 0 ? Wq : slot == 1 ? Wk : Wv) + (long)i * C * C + (long)n * C + c4;
    float4 v = *(const float4*)src;
    bf16x4v d = {(bf16)v.x, (bf16)v.y, (bf16)v.z, (bf16)v.w};
    *(bf16x4v*)(wqkv_all + (((long)(i * 3 + slot) * 512 + n) * 512 + c4)) = d;
  } else if (idx < nQ + nO) {
    long j = idx - nQ;
    float4 v = *(const float4*)(Wo + j * 4);
    bf16x4v d = {(bf16)v.x, (bf16)v.y, (bf16)v.z, (bf16)v.w};
    *(bf16x4v*)(wo_all + j * 4) = d;
  }
}

// ---------------------------------------------------------------------------
// Merged K=3 weight conversion: W1 (N=F,Kd=C) + W2 (N=C,Kd=F), coalesced
// 2-wide (each thread reads 6 contiguous floats, writes bf16x2 to 3 planes).
// ---------------------------------------------------------------------------
__global__ __launch_bounds__(256) void cvt_w12_kernel(
    const float* __restrict__ W1, const float* __restrict__ W2,
    bf16* __restrict__ w1_all, bf16* __restrict__ w2_all)
{
  const long n1t = (long)L * F * C / 2;     // W1 items
  const long n2t = (long)L * C * F / 2;     // W2 items
  long idx = (long)blockIdx.x * 256 + threadIdx.x;
  const float* src;
  bf16* dst;
  int N, Kd;
  if (idx < n1t) {
    src = W1; dst = w1_all; N = F; Kd = C;
  } else if (idx < n1t + n2t) {
    idx -= n1t;
    src = W2; dst = w2_all; N = C; Kd = F;
  } else {
    return;
  }
  const int half = Kd >> 1;
  int c2 = (int)(idx % half) * 2;
  long r = idx / half;
  int n = (int)(r % N);
  int i = (int)(r / N);
  const float* s = src + ((long)i * N * Kd + (long)n * Kd + c2) * 3;
  float v0 = s[0], v1 = s[1], v2 = s[2], v3 = s[3], v4 = s[4], v5 = s[5];
  long plane = (long)N * Kd;
  long baseo = (long)i * 3 * plane + (long)n * Kd + c2;
  bf16x2 d0 = {(bf16)v0, (bf16)v3};
  bf16x2 d1 = {(bf16)v1, (bf16)v4};
  bf16x2 d2 = {(bf16)v2, (bf16)v5};
  *(bf16x2*)(dst + baseo)             = d0;
  *(bf16x2*)(dst + baseo + plane)     = d1;
  *(bf16x2*)(dst + baseo + 2 * plane) = d2;
}

// ---------------------------------------------------------------------------
extern "C" void kernel_launch(void* const* d_in, const int* in_sizes, int n_in,
                              void* d_out, int out_size, void* d_ws, size_t ws_size,
                              hipStream_t stream)
{
  const float* xin = (const float*)d_in[0];
  const float* msk = (const float*)d_in[1];
  const float* Wq  = (const float*)d_in[2];
  const float* bq  = (const float*)d_in[3];
  const float* Wk  = (const float*)d_in[4];
  const float* bk  = (const float*)d_in[5];
  const float* Wv  = (const float*)d_in[6];
  const float* bv  = (const float*)d_in[7];
  const float* Wo  = (const float*)d_in[8];
  const float* bo  = (const float*)d_in[9];
  const float* g1  = (const float*)d_in[10];
  const float* be1 = (const float*)d_in[11];
  const float* W1  = (const float*)d_in[12];
  const float* c1  = (const float*)d_in[13];
  const float* W2  = (const float*)d_in[14];
  const float* c2  = (const float*)d_in[15];
  const float* g2  = (const float*)d_in[16];
  const float* be2 = (const float*)d_in[17];

  size_t off = 0;
  char* base = (char*)d_ws;
  auto alloc = [&](size_t bytes) -> char* {
    char* r = base + off;
    off = (off + bytes + 1023) & ~(size_t)1023;
    return r;
  };
  bf16* x      = (bf16*)alloc((size_t)B * T * C * 2);     // bf16 residual stream
  float* ropeC = (float*)alloc((size_t)T * 16 * 4);
  float* ropeS = (float*)alloc((size_t)T * 16 * 4);
  bf16* xm  = (bf16*)alloc((size_t)B * TP * C * 2);
  bf16* hb  = (bf16*)alloc((size_t)B * TP * F * 2);
  bf16* q   = (bf16*)alloc((size_t)B * T * C * 2);
  bf16* k   = (bf16*)alloc((size_t)B * T * C * 2);
  bf16* vT  = (bf16*)alloc((size_t)B * T * C * 2);
  bf16* o   = (bf16*)alloc((size_t)B * T * C * 2);
  bf16* yb  = (bf16*)alloc((size_t)B * T * C * 2);
  bf16* wqkv_all = (bf16*)alloc((size_t)L * 3 * C * C * 2);
  bf16* wo_all   = (bf16*)alloc((size_t)L * C * C * 2);
  bf16* w1_all   = (bf16*)alloc((size_t)L * 3 * F * C * 2);
  bf16* w2_all   = (bf16*)alloc((size_t)L * 3 * C * F * 2);
  float* bqkv_all = (float*)alloc((size_t)L * 1536 * 4);
  (void)in_sizes; (void)n_in; (void)out_size; (void)ws_size;

  // ---- one-time prologue (consolidated: 8 dispatches -> 4) ----
  {
    long tot = (long)B * 18 * (C + F) + (long)T * 16 + (long)L * 1536;
    prologue_misc_kernel<<<(int)((tot + 255) / 256), 256, 0, stream>>>(
        xm, hb, ropeC, ropeS, bq, bk, bv, bqkv_all);
  }
  transpose_in_kernel<<<dim3(T / 32, C / 32, B), dim3(32, 8), 0, stream>>>(xin, msk, x, xm);
  {
    long tot = (long)L * 3 * C * C / 4 + (long)L * C * C / 4;
    cvt_qkvo_kernel<<<(int)((tot + 255) / 256), 256, 0, stream>>>(
        Wq, Wk, Wv, Wo, wqkv_all, wo_all);
  }
  {
    long tot = (long)L * F * C / 2 + (long)L * C * F / 2;
    cvt_w12_kernel<<<(int)((tot + 255) / 256), 256, 0, stream>>>(
        W1, W2, w1_all, w2_all);
  }

  for (int i = 0; i < L; ++i) {
    const bf16* wqkv = wqkv_all + (long)i * 3 * C * C;
    const bf16* wo   = wo_all + (long)i * C * C;
    const bf16* w1b  = w1_all + (long)i * 3 * F * C;
    const bf16* w2b  = w2_all + (long)i * 3 * C * F;
    const float* bqkv = bqkv_all + (long)i * 1536;

    // fused QKV projection (N=1536) + RoPE in epilogue; v stored transposed
    gemm_kernel<64, 128, 1, 2, false, false, 1, false, false, 4, 64>
        <<<dim3(16, 12, B), 256, 0, stream>>>(
        xm + C, wqkv, bqkv, msk, q, k, vT,
        C, C, C, C, 0,
        (long)TP * C, 0, 0, 0, (long)T * C, 0, 0, ropeC, ropeS);

    flash_kernel<<<dim3(T / 64, B * H), 256, 0, stream>>>(q, k, vT, msk, o);

    // O projection (batch flattened: M = B*T) — BK=64
    gemm_kernel<64, 64, 1, 0, false, false, 1, false, false, 4, 64>
        <<<dim3(64, 8, 1), 256, 0, stream>>>(
        o, wo, bo + (size_t)i * C, msk, yb, nullptr, nullptr,
        C, C, C, C, 0,
        0, 0, 0, 0, 0, 0, 0, nullptr, nullptr);

    ln_kernel<<<B * T / 4, 256, 0, stream>>>(x, yb, g1 + (size_t)i * C, be1 + (size_t)i * C,
                                             msk, 1, 0, x, xm);

    // FFN conv1 (K=3, relu, masked output) — 128x128 tile, BK=32 (R10-proven)
    gemm_kernel<128, 128, 3, 0, true, true, 1, false, false, 2, 32>
        <<<dim3(8, 16, B), 256, 0, stream>>>(
        xm, w1b, c1 + (size_t)i * F, msk, hb + F, nullptr, nullptr,
        C, C, F, C, (long)F * C,
        (long)TP * C, 0, 0, 0, (long)TP * F, 0, 0, nullptr, nullptr);

    // FFN conv2 (K=3) — 64x64 tile, BK=64
    gemm_kernel<64, 64, 3, 0, false, false, 1, false, false, 2, 64>
        <<<dim3(16, 8, B), 256, 0, stream>>>(
        hb, w2b, c2 + (size_t)i * C, msk, yb, nullptr, nullptr,
        F, F, C, F, (long)C * F,
        (long)TP * F, 0, 0, 0, (long)T * C, 0, 0, nullptr, nullptr);

    ln_kernel<<<B * T / 4, 256, 0, stream>>>(x, yb, g2 + (size_t)i * C, be2 + (size_t)i * C,
                                             msk, 0, 1, x, xm);
  }

  transpose_out_kernel<<<dim3(T / 32, C / 32, B), dim3(32, 8), 0, stream>>>(x, msk, (float*)d_out);
}

// Round 19
// 764.215 us; speedup vs baseline: 1.0296x; 1.0004x over previous
//
#include <hip/hip_runtime.h>

typedef __bf16 bf16;
typedef __bf16 bf16x2 __attribute__((ext_vector_type(2)));
typedef __bf16 bf16x8 __attribute__((ext_vector_type(8)));
typedef __bf16 bf16x4v __attribute__((ext_vector_type(4)));
typedef float f32x4 __attribute__((ext_vector_type(4)));

constexpr int B = 4, C = 512, T = 1024, H = 8, F = 2048, L = 6;
constexpr int TP = T + 18;               // padded rows: row0 = zero, rows T+1..T+17 zero
constexpr float SCALE = 0.125f, EPS = 1e-4f;

// ---------------------------------------------------------------------------
// global -> LDS staging, 64B rows (BK=32 tiles: 32 bf16 k-slice per row)
// LDS linear; swizzle applied on the per-lane GLOBAL source (involution),
// matched by the same XOR on the ds_read side.
// ---------------------------------------------------------------------------
__device__ __forceinline__ void stage_rows(const char* g, long strideB, char* lds,
                                           int nChunks, int tid) {
  const int wave = tid >> 6, lane = tid & 63;
  for (int c = wave; c < nChunks; c += 4) {
    int row = (c << 4) + (lane >> 2);
    int kq = (lane & 3) ^ ((row >> 1) & 3);
    const char* src = g + (long)row * strideB + kq * 16;
    char* dst = lds + ((long)c << 10);
    __builtin_amdgcn_global_load_lds((const __attribute__((address_space(1))) void*)src,
                                     (__attribute__((address_space(3))) void*)dst,
                                     16, 0, 0);
  }
}

// 128B rows (BK=64 tiles / flash: 64 bf16 per row).
// LDS[row][slot16] = G[row][slot ^ (row&7)].
__device__ __forceinline__ void stage_rows128(const char* g, long strideB, char* lds,
                                              int nChunks, int tid) {
  const int wave = tid >> 6, lane = tid & 63;
  for (int c = wave; c < nChunks; c += 4) {
    int row = (c << 3) + (lane >> 3);
    int kq = (lane & 7) ^ ((lane >> 3) & 7);
    const char* src = g + (long)row * strideB + kq * 16;
    char* dst = lds + ((long)c << 10);
    __builtin_amdgcn_global_load_lds((const __attribute__((address_space(1))) void*)src,
                                     (__attribute__((address_space(3))) void*)dst,
                                     16, 0, 0);
  }
}

// ---------------------------------------------------------------------------
// NT GEMM, 2-phase prefetch double-buffered LDS (proven path).
// D[m][n] = sum_k A[m][k] * Bw[n][k]  (+ kw-shifted A rows for KW=3)
// BK: 32 (64B rows) or 64 (128B rows; halves barrier-drain events — proven
//     on FFN2 (R9) and QKV/oproj (R10); NOT at the cost of tile size (R11)).
// EPI: 0 = bf16 [m][ldo] (+bias, relu, maskM opts)
//      2 = QKV split with fused RoPE: n<512 -> O(q), <1024 -> O2(k),
//          else O3 = vT[n-1024][m]
// ---------------------------------------------------------------------------
template <int BM, int BN, int KW, int EPI, bool RELU, bool MASKM, int ZD,
          bool AZL, bool OZL, int MINW, int BK>
__global__ __launch_bounds__(256, MINW) void gemm_kernel(
    const bf16* __restrict__ A, const bf16* __restrict__ Bw,
    const float* __restrict__ bias, const float* __restrict__ mask,
    bf16* __restrict__ O, bf16* __restrict__ O2, bf16* __restrict__ O3,
    int lda, int ldb, int ldo, int K, long bSlice,
    long aZ1, long aZ2, long bZ1, long bZ2, long oZ1, long oZ2, int zoff,
    const float* __restrict__ ropeC, const float* __restrict__ ropeS)
{
  constexpr int WTM = BM / 2, WTN = BN / 2, FM = WTM / 16, FN = WTN / 16;
  constexpr int RA = (KW == 3) ? BM + 16 : BM;
  constexpr int ROWB = (BK == 64) ? 128 : 64;
  constexpr int ACH = RA * ROWB / 1024;
  constexpr int BCHS = BN * ROWB / 1024;
  constexpr int TCH = ACH + KW * BCHS;
  __shared__ __align__(1024) bf16 sBuf[2][TCH * 512];

  const int tid = threadIdx.x;
  const int zl = blockIdx.z, zg = zl + zoff;
  const int zb = zg / ZD, zh = zg % ZD;
  const long aOff = AZL ? (long)zl * aZ1 : (long)zb * aZ1 + (long)zh * aZ2;
  const long bOff = (long)zb * bZ1 + (long)zh * bZ2;
  const long oOff = OZL ? (long)zl * oZ1 : (long)zb * oZ1 + (long)zh * oZ2;
  const int m0 = blockIdx.x * BM, n0 = blockIdx.y * BN;
  const bf16* Ab = A + aOff + (long)m0 * lda;
  const bf16* Bb = Bw + bOff + (long)n0 * ldb;

  const int wid = tid >> 6, lane = tid & 63;
  const int wm = wid >> 1, wn = wid & 1;
  const int l16 = lane & 15, q4 = lane >> 4;

  f32x4 acc[FM][FN] = {};

  auto STAGE = [&](int k0, int buf) {
    char* sa = (char*)sBuf[buf];
    if constexpr (BK == 64) {
      stage_rows128((const char*)(Ab + k0), (long)lda * 2, sa, ACH, tid);
      #pragma unroll
      for (int kw = 0; kw < KW; ++kw)
        stage_rows128((const char*)(Bb + (long)kw * bSlice + k0), (long)ldb * 2,
                      sa + (ACH + kw * BCHS) * 1024, BCHS, tid);
    } else {
      stage_rows((const char*)(Ab + k0), (long)lda * 2, sa, ACH, tid);
      #pragma unroll
      for (int kw = 0; kw < KW; ++kw)
        stage_rows((const char*)(Bb + (long)kw * bSlice + k0), (long)ldb * 2,
                   sa + (ACH + kw * BCHS) * 1024, BCHS, tid);
    }
  };

  auto COMPUTE = [&](int buf) {
    const char* sa = (const char*)sBuf[buf];
    const char* sb = sa + ACH * 1024;
    if constexpr (BK == 64) {
      #pragma unroll
      for (int kw = 0; kw < KW; ++kw) {
        #pragma unroll
        for (int kk2 = 0; kk2 < 2; ++kk2) {
          bf16x8 af[FM], bfr[FN];
          #pragma unroll
          for (int fm = 0; fm < FM; ++fm) {
            const int row = wm * WTM + fm * 16 + l16 + (KW == 3 ? kw : 0);
            unsigned off = (unsigned)(kk2 * 64 + q4 * 16) ^ ((unsigned)(row & 7) << 4);
            af[fm] = *(const bf16x8*)(sa + row * 128 + off);
          }
          #pragma unroll
          for (int fn = 0; fn < FN; ++fn) {
            const int rn = wn * WTN + fn * 16 + l16;
            unsigned off = (unsigned)(kk2 * 64 + q4 * 16) ^ ((unsigned)(rn & 7) << 4);
            bfr[fn] = *(const bf16x8*)(sb + kw * BCHS * 1024 + rn * 128 + off);
          }
          #pragma unroll
          for (int fm = 0; fm < FM; ++fm)
            #pragma unroll
            for (int fn = 0; fn < FN; ++fn)
              acc[fm][fn] = __builtin_amdgcn_mfma_f32_16x16x32_bf16(af[fm], bfr[fn],
                                                                    acc[fm][fn], 0, 0, 0);
        }
      }
    } else {
      #pragma unroll
      for (int kw = 0; kw < KW; ++kw) {
        bf16x8 af[FM], bfr[FN];
        #pragma unroll
        for (int fm = 0; fm < FM; ++fm) {
          int row = wm * WTM + fm * 16 + l16 + (KW == 3 ? kw : 0);
          unsigned ad = (unsigned)(row * 64 + q4 * 16);
          ad ^= ((ad >> 7) & 3u) << 4;
          af[fm] = *(const bf16x8*)(sa + ad);
        }
        #pragma unroll
        for (int fn = 0; fn < FN; ++fn) {
          int rn = wn * WTN + fn * 16 + l16;
          unsigned bd = (unsigned)(rn * 64 + q4 * 16);
          bd ^= ((bd >> 7) & 3u) << 4;
          bfr[fn] = *(const bf16x8*)(sb + kw * BCHS * 1024 + bd);
        }
        #pragma unroll
        for (int fm = 0; fm < FM; ++fm)
          #pragma unroll
          for (int fn = 0; fn < FN; ++fn)
            acc[fm][fn] = __builtin_amdgcn_mfma_f32_16x16x32_bf16(af[fm], bfr[fn],
                                                                  acc[fm][fn], 0, 0, 0);
      }
    }
  };

  STAGE(0, 0);
  __syncthreads();
  int cur = 0;
  for (int k0 = BK; k0 < K; k0 += BK) {
    STAGE(k0, cur ^ 1);
    COMPUTE(cur);
    __syncthreads();
    cur ^= 1;
  }
  COMPUTE(cur);

  // ---- epilogue: C/D layout col=lane&15, row=(lane>>4)*4+i ----
  float varr[FN][FM][4];
  #pragma unroll
  for (int fn = 0; fn < FN; ++fn) {
    const int nl = n0 + wn * WTN + fn * 16 + l16;
    const float bv = (bias == nullptr) ? 0.f : bias[nl];
    #pragma unroll
    for (int fm = 0; fm < FM; ++fm) {
      const int mb = m0 + wm * WTM + fm * 16 + q4 * 4;
      #pragma unroll
      for (int i = 0; i < 4; ++i) {
        float t = acc[fm][fn][i] + bv;
        if (RELU) t = fmaxf(t, 0.f);
        if (MASKM) t *= mask[(long)zb * T + mb + i];
        varr[fn][fm][i] = t;
      }
    }
  }

  if constexpr (EPI == 2) {
    if (n0 + wn * WTN < 1024) {
      #pragma unroll
      for (int fm = 0; fm < FM; ++fm) {
        const int mb = m0 + wm * WTM + fm * 16 + q4 * 4;
        #pragma unroll
        for (int i = 0; i < 4; ++i) {
          const int t = mb + i;
          float cv = ropeC[t * 16 + l16], sv = ropeS[t * 16 + l16];
          float a = varr[0][fm][i], b2 = varr[1][fm][i];
          varr[0][fm][i] = a * cv - b2 * sv;
          varr[1][fm][i] = b2 * cv + a * sv;
        }
      }
    }
  }

  #pragma unroll
  for (int fn = 0; fn < FN; ++fn) {
    const int nl = n0 + wn * WTN + fn * 16 + l16;
    #pragma unroll
    for (int fm = 0; fm < FM; ++fm) {
      const int mb = m0 + wm * WTM + fm * 16 + q4 * 4;
      if constexpr (EPI == 2) {
        if (nl < 1024) {
          bf16* dst = (nl < 512 ? O : O2) + oOff + (nl & 511);
          #pragma unroll
          for (int i = 0; i < 4; ++i)
            dst[(long)(mb + i) * C] = (bf16)varr[fn][fm][i];
        } else {
          bf16x4v tv;
          #pragma unroll
          for (int i = 0; i < 4; ++i) tv[i] = (bf16)varr[fn][fm][i];
          *(bf16x4v*)(O3 + oOff + (long)(nl - 1024) * T + mb) = tv;
        }
      } else {
        bf16* dst = O + oOff;
        #pragma unroll
        for (int i = 0; i < 4; ++i)
          dst[(long)(mb + i) * ldo + nl] = (bf16)varr[fn][fm][i];
      }
    }
  }
}

// ---------------------------------------------------------------------------
// Flash attention: one block = 64 q-rows x one (b,h). 4 waves x 16 q-rows.
// XCD-aware work swizzle (T1). Fixed-base softmax: p = exp(s - 8).
// ---------------------------------------------------------------------------
__global__ __launch_bounds__(256, 3) void flash_kernel(
    const bf16* __restrict__ q, const bf16* __restrict__ k,
    const bf16* __restrict__ vT, const float* __restrict__ mask,
    bf16* __restrict__ o)
{
  __shared__ __align__(1024) char sQ[64 * 128];
  __shared__ __align__(1024) char sK[2][64 * 128];
  __shared__ __align__(1024) char sV[2][64 * 128];
  __shared__ __align__(1024) char sP[4][16 * 128];

  const int tid = threadIdx.x;
  const int w = tid >> 6, lane = tid & 63;
  const int l16 = lane & 15, q4 = lane >> 4;
  // dispatch-linear id -> XCD-chunked work id (bijective on 512 = 8*64)
  const int g = blockIdx.y * 16 + blockIdx.x;
  const int swz = (g & 7) * 64 + (g >> 3);
  const int q0 = (swz & 15) * 64;
  const int bh = swz >> 4;
  const int b = bh >> 3, h = bh & 7;

  const bf16* qb = q + ((long)b * T + q0) * C + h * 64;
  const bf16* kb = k + (long)b * T * C + h * 64;
  const bf16* vb = vT + (long)b * C * T + (long)h * 64 * T;

  stage_rows128((const char*)qb, (long)C * 2, sQ, 8, tid);
  stage_rows128((const char*)kb, (long)C * 2, sK[0], 8, tid);
  stage_rows128((const char*)vb, (long)T * 2, sV[0], 8, tid);
  __syncthreads();

  bf16x8 af_q[2];
  {
    const int r = w * 16 + l16;
    #pragma unroll
    for (int kk = 0; kk < 2; ++kk) {
      unsigned off = (unsigned)(kk * 64 + q4 * 16) ^ ((unsigned)(r & 7) << 4);
      af_q[kk] = *(const bf16x8*)(sQ + r * 128 + off);
    }
  }

  float mq[4];
  #pragma unroll
  for (int i = 0; i < 4; ++i)
    mq[i] = mask[(long)b * T + q0 + w * 16 + q4 * 4 + i];

  f32x4 accO[4] = {};
  float lrun[4] = {0.f, 0.f, 0.f, 0.f};   // per-lane partial row sums
  char* sPw = sP[w];

  int cur = 0;
  for (int it = 0; it < 16; ++it) {
    if (it < 15) {
      stage_rows128((const char*)(kb + (long)(it + 1) * 64 * C), (long)C * 2, sK[cur ^ 1], 8, tid);
      stage_rows128((const char*)(vb + (it + 1) * 64), (long)T * 2, sV[cur ^ 1], 8, tid);
    }
    f32x4 s[4] = {};
    #pragma unroll
    for (int kk = 0; kk < 2; ++kk) {
      #pragma unroll
      for (int fn = 0; fn < 4; ++fn) {
        const int rn = fn * 16 + l16;
        unsigned off = (unsigned)(kk * 64 + q4 * 16) ^ ((unsigned)(rn & 7) << 4);
        bf16x8 kf = *(const bf16x8*)(sK[cur] + rn * 128 + off);
        s[fn] = __builtin_amdgcn_mfma_f32_16x16x32_bf16(af_q[kk], kf, s[fn], 0, 0, 0);
      }
    }
    float mk[4];
    #pragma unroll
    for (int fn = 0; fn < 4; ++fn)
      mk[fn] = mask[(long)b * T + it * 64 + fn * 16 + l16];
    // fixed-base exp: p = exp(s*SCALE - 8); masked -> exp(-10008) = 0
    #pragma unroll
    for (int fn = 0; fn < 4; ++fn)
      #pragma unroll
      for (int i = 0; i < 4; ++i) {
        float xval = s[fn][i] * SCALE;
        float sv = (mq[i] * mk[fn] > 0.f) ? xval : -10000.f;
        float p = __expf(sv - 8.f);
        lrun[i] += p;
        const int row = q4 * 4 + i;
        unsigned off = (unsigned)((fn * 16 + l16) * 2) ^ ((unsigned)(row & 7) << 4);
        *(bf16*)(sPw + row * 128 + off) = (bf16)p;
      }
    #pragma unroll
    for (int kk = 0; kk < 2; ++kk) {
      unsigned poff = (unsigned)(kk * 64 + q4 * 16) ^ ((unsigned)(l16 & 7) << 4);
      bf16x8 pf = *(const bf16x8*)(sPw + l16 * 128 + poff);
      #pragma unroll
      for (int fn = 0; fn < 4; ++fn) {
        const int rn = fn * 16 + l16;
        unsigned off = (unsigned)(kk * 64 + q4 * 16) ^ ((unsigned)(rn & 7) << 4);
        bf16x8 vf = *(const bf16x8*)(sV[cur] + rn * 128 + off);
        accO[fn] = __builtin_amdgcn_mfma_f32_16x16x32_bf16(pf, vf, accO[fn], 0, 0, 0);
      }
    }
    __syncthreads();
    cur ^= 1;
  }

  // single end-of-loop row-sum reduction over the 16 l16 lanes
  float linv[4];
  #pragma unroll
  for (int i = 0; i < 4; ++i) {
    #pragma unroll
    for (int st = 1; st < 16; st <<= 1) lrun[i] += __shfl_xor(lrun[i], st, 64);
    linv[i] = 1.f / fmaxf(lrun[i], 1e-20f);   // guard fully-masked rows
  }
  #pragma unroll
  for (int fn = 0; fn < 4; ++fn)
    #pragma unroll
    for (int i = 0; i < 4; ++i)
      o[((long)b * T + q0 + w * 16 + q4 * 4 + i) * C + h * 64 + fn * 16 + l16] =
          (bf16)(accO[fn][i] * linv[i]);
}

// ---------------- fused residual + LayerNorm over contiguous C ----------------
// Residual stream x is bf16 (2% tolerance admits the ~0.2%/layer rounding;
// LN renormalizes each layer so errors don't compound multiplicatively).
__global__ __launch_bounds__(256) void ln_kernel(
    const bf16* __restrict__ x, const bf16* __restrict__ y,
    const float* __restrict__ gamma, const float* __restrict__ beta,
    const float* __restrict__ mask, int maskA, int maskY,
    bf16* __restrict__ xout, bf16* __restrict__ xm)
{
  const int w = threadIdx.x >> 6, lane = threadIdx.x & 63;
  const long row = (long)blockIdx.x * 4 + w;
  const int b = (int)(row >> 10), t = (int)(row & 1023);
  const bf16* xr = x + row * C;
  const bf16* yr = y + row * C;
  const float m = mask[(long)b * T + t];
  const float fa = maskA ? m : 1.f, fy = maskY ? m : 1.f;
  bf16x8 xv = *(const bf16x8*)(xr + lane * 8);
  bf16x8 yv = *(const bf16x8*)(yr + lane * 8);
  float vals[8];
  float sum = 0.f, sq = 0.f;
  #pragma unroll
  for (int i = 0; i < 8; ++i) {
    vals[i] = (float)xv[i] * fa + (float)yv[i] * fy;
    sum += vals[i]; sq += vals[i] * vals[i];
  }
  #pragma unroll
  for (int s = 1; s < 64; s <<= 1) {
    sum += __shfl_xor(sum, s, 64);
    sq  += __shfl_xor(sq, s, 64);
  }
  float mean = sum * (1.f / C);
  float rstd = rsqrtf(sq * (1.f / C) - mean * mean + EPS);
  float4 g0 = *(const float4*)(gamma + lane * 8), g1v = *(const float4*)(gamma + lane * 8 + 4);
  float4 b0 = *(const float4*)(beta + lane * 8),  b1v = *(const float4*)(beta + lane * 8 + 4);
  float gg[8] = {g0.x, g0.y, g0.z, g0.w, g1v.x, g1v.y, g1v.z, g1v.w};
  float bb[8] = {b0.x, b0.y, b0.z, b0.w, b1v.x, b1v.y, b1v.z, b1v.w};
  bf16x8 xov, xmv;
  #pragma unroll
  for (int i = 0; i < 8; ++i) {
    float o = (vals[i] - mean) * rstd * gg[i] + bb[i];
    xov[i] = (bf16)o;
    xmv[i] = (bf16)(o * m);
  }
  *(bf16x8*)(xout + row * C + lane * 8) = xov;
  *(bf16x8*)(xm + ((long)b * TP + t + 1) * C + lane * 8) = xmv;
}

// ---------------- transposes [b][C][T] <-> [b][t][C] ----------------
__global__ __launch_bounds__(256) void transpose_in_kernel(const float* __restrict__ xin,
                                                           const float* __restrict__ mask,
                                                           bf16* __restrict__ x,
                                                           bf16* __restrict__ xm) {
  __shared__ float tile[32][33];
  int tx = threadIdx.x, ty = threadIdx.y;
  int t0 = blockIdx.x * 32, c0 = blockIdx.y * 32, b = blockIdx.z;
  #pragma unroll
  for (int i = 0; i < 4; ++i)
    tile[ty + i * 8][tx] = xin[((long)b * C + c0 + ty + i * 8) * T + t0 + tx];
  __syncthreads();
  #pragma unroll
  for (int i = 0; i < 4; ++i) {
    int t = t0 + ty + i * 8;
    float val = tile[tx][ty + i * 8];
    float m = mask[(long)b * T + t];
    x[((long)b * T + t) * C + c0 + tx] = (bf16)val;
    xm[((long)b * TP + t + 1) * C + c0 + tx] = (bf16)(val * m);
  }
}

__global__ __launch_bounds__(256) void transpose_out_kernel(const bf16* __restrict__ x,
                                                            const float* __restrict__ mask,
                                                            float* __restrict__ out) {
  __shared__ float tile[32][33];
  int tx = threadIdx.x, ty = threadIdx.y;
  int t0 = blockIdx.x * 32, c0 = blockIdx.y * 32, b = blockIdx.z;
  #pragma unroll
  for (int i = 0; i < 4; ++i)
    tile[ty + i * 8][tx] = (float)x[((long)b * T + t0 + ty + i * 8) * C + c0 + tx];
  __syncthreads();
  #pragma unroll
  for (int i = 0; i < 4; ++i) {
    int t = t0 + tx;
    out[((long)b * C + c0 + ty + i * 8) * T + t] = tile[tx][ty + i * 8] * mask[(long)b * T + t];
  }
}

// ---------------------------------------------------------------------------
// Merged prologue misc: zero halo pads + RoPE table + bias concat (one grid,
// index-range dispatch; logic identical to the three former kernels).
// ---------------------------------------------------------------------------
__global__ __launch_bounds__(256) void prologue_misc_kernel(
    bf16* __restrict__ xm, bf16* __restrict__ hb,
    float* __restrict__ cosT, float* __restrict__ sinT,
    const float* __restrict__ bq, const float* __restrict__ bk,
    const float* __restrict__ bv, float* __restrict__ bqkv_all)
{
  const long n1 = (long)B * 18 * C;
  const long n2 = (long)B * 18 * F;
  const long nR = (long)T * 16;
  const long nB = (long)L * 1536;
  long idx = (long)blockIdx.x * 256 + threadIdx.x;
  if (idx < n1) {
    int c = (int)(idx % C); int r = (int)((idx / C) % 18); int b = (int)(idx / (18L * C));
    int p = (r == 0) ? 0 : (T + r);
    xm[((long)b * TP + p) * C + c] = (bf16)0.f;
  } else if (idx < n1 + n2) {
    long j = idx - n1;
    int c = (int)(j % F); int r = (int)((j / F) % 18); int b = (int)(j / (18L * F));
    int p = (r == 0) ? 0 : (T + r);
    hb[((long)b * TP + p) * F + c] = (bf16)0.f;
  } else if (idx < n1 + n2 + nR) {
    long j = idx - n1 - n2;
    int t = (int)(j >> 4), jj = (int)(j & 15);
    float theta = powf(10000.f, -(float)jj / 16.f);
    float s, c;
    sincosf((float)t * theta, &s, &c);
    cosT[j] = c;
    sinT[j] = s;
  } else if (idx < n1 + n2 + nR + nB) {
    long j2 = idx - n1 - n2 - nR;
    int j = (int)(j2 % 1536), i = (int)(j2 / 1536);
    float v = (j < 512) ? bq[i * 512 + j] : (j < 1024) ? bk[i * 512 + j - 512]
                                                       : bv[i * 512 + j - 1024];
    bqkv_all[j2] = v;
  }
}

// ---------------------------------------------------------------------------
// Merged square-weight conversion: qkv (interleaved [i][slot][n][c]) + wo.
// 8 floats/thread: 2x float4 read -> 1x bf16x8 (16B) write.
// ---------------------------------------------------------------------------
__global__ __launch_bounds__(256) void cvt_qkvo_kernel(
    const float* __restrict__ Wq, const float* __restrict__ Wk,
    const float* __restrict__ Wv, const float* __restrict__ Wo,
    bf16* __restrict__ wqkv_all, bf16* __restrict__ wo_all)
{
  const long nQ = (long)L * 3 * C * C / 8;
  const long nO = (long)L * C * C / 8;
  long idx = (long)blockIdx.x * 256 + threadIdx.x;
  if (idx < nQ) {
    int c8 = (int)(idx & 63) * 8;                 // C/8 = 64 c-groups
    int n = (int)((idx >> 6) & 511);
    int s2 = (int)(idx >> 15);                    // 512*64 = 2^15 per (i,slot)
    int slot = s2 % 3, i = s2 / 3;
    const float* src = (slot == 0 ? Wq : slot == 1 ? Wk : Wv) + (long)i * C * C + (long)n * C + c8;
    float4 a = *(const float4*)src;
    float4 b = *(const float4*)(src + 4);
    bf16x8 d = {(bf16)a.x, (bf16)a.y, (bf16)a.z, (bf16)a.w,
                (bf16)b.x, (bf16)b.y, (bf16)b.z, (bf16)b.w};
    *(bf16x8*)(wqkv_all + (((long)(i * 3 + slot) * 512 + n) * 512 + c8)) = d;
  } else if (idx < nQ + nO) {
    long j = idx - nQ;
    const float* src = Wo + j * 8;
    float4 a = *(const float4*)src;
    float4 b = *(const float4*)(src + 4);
    bf16x8 d = {(bf16)a.x, (bf16)a.y, (bf16)a.z, (bf16)a.w,
                (bf16)b.x, (bf16)b.y, (bf16)b.z, (bf16)b.w};
    *(bf16x8*)(wo_all + j * 8) = d;
  }
}

// ---------------------------------------------------------------------------
// Merged K=3 weight conversion: W1 (N=F,Kd=C) + W2 (N=C,Kd=F).
// 8 c-values/thread: 24 contiguous floats via 6x aligned float4 (96B stride
// with c8 % 8 == 0 keeps 16B alignment), one bf16x8 (16B) write per k-plane.
// Was 2-wide (24B scalar-ish reads + 4B writes) -> 2.5 TB/s; this targets ~5+.
// ---------------------------------------------------------------------------
__global__ __launch_bounds__(256) void cvt_w12_kernel(
    const float* __restrict__ W1, const float* __restrict__ W2,
    bf16* __restrict__ w1_all, bf16* __restrict__ w2_all)
{
  const long n1t = (long)L * F * C / 8;     // W1 items (8-wide)
  const long n2t = (long)L * C * F / 8;     // W2 items
  long idx = (long)blockIdx.x * 256 + threadIdx.x;
  const float* src;
  bf16* dst;
  int N, Kd;
  if (idx < n1t) {
    src = W1; dst = w1_all; N = F; Kd = C;
  } else if (idx < n1t + n2t) {
    idx -= n1t;
    src = W2; dst = w2_all; N = C; Kd = F;
  } else {
    return;
  }
  const int eighth = Kd >> 3;
  int c8 = (int)(idx % eighth) * 8;
  long r = idx / eighth;
  int n = (int)(r % N);
  int i = (int)(r / N);
  const float* s = src + ((long)i * N * Kd + (long)n * Kd + c8) * 3;
  float4 f[6];
  #pragma unroll
  for (int t = 0; t < 6; ++t) f[t] = *(const float4*)(s + t * 4);
  const float* ss = (const float*)f;
  long plane = (long)N * Kd;
  long baseo = (long)i * 3 * plane + (long)n * Kd + c8;
  bf16x8 d0, d1, d2;
  #pragma unroll
  for (int j = 0; j < 8; ++j) {
    d0[j] = (bf16)ss[3 * j];
    d1[j] = (bf16)ss[3 * j + 1];
    d2[j] = (bf16)ss[3 * j + 2];
  }
  *(bf16x8*)(dst + baseo)             = d0;
  *(bf16x8*)(dst + baseo + plane)     = d1;
  *(bf16x8*)(dst + baseo + 2 * plane) = d2;
}

// ---------------------------------------------------------------------------
extern "C" void kernel_launch(void* const* d_in, const int* in_sizes, int n_in,
                              void* d_out, int out_size, void* d_ws, size_t ws_size,
                              hipStream_t stream)
{
  const float* xin = (const float*)d_in[0];
  const float* msk = (const float*)d_in[1];
  const float* Wq  = (const float*)d_in[2];
  const float* bq  = (const float*)d_in[3];
  const float* Wk  = (const float*)d_in[4];
  const float* bk  = (const float*)d_in[5];
  const float* Wv  = (const float*)d_in[6];
  const float* bv  = (const float*)d_in[7];
  const float* Wo  = (const float*)d_in[8];
  const float* bo  = (const float*)d_in[9];
  const float* g1  = (const float*)d_in[10];
  const float* be1 = (const float*)d_in[11];
  const float* W1  = (const float*)d_in[12];
  const float* c1  = (const float*)d_in[13];
  const float* W2  = (const float*)d_in[14];
  const float* c2  = (const float*)d_in[15];
  const float* g2  = (const float*)d_in[16];
  const float* be2 = (const float*)d_in[17];

  size_t off = 0;
  char* base = (char*)d_ws;
  auto alloc = [&](size_t bytes) -> char* {
    char* r = base + off;
    off = (off + bytes + 1023) & ~(size_t)1023;
    return r;
  };
  bf16* x      = (bf16*)alloc((size_t)B * T * C * 2);     // bf16 residual stream
  float* ropeC = (float*)alloc((size_t)T * 16 * 4);
  float* ropeS = (float*)alloc((size_t)T * 16 * 4);
  bf16* xm  = (bf16*)alloc((size_t)B * TP * C * 2);
  bf16* hb  = (bf16*)alloc((size_t)B * TP * F * 2);
  bf16* q   = (bf16*)alloc((size_t)B * T * C * 2);
  bf16* k   = (bf16*)alloc((size_t)B * T * C * 2);
  bf16* vT  = (bf16*)alloc((size_t)B * T * C * 2);
  bf16* o   = (bf16*)alloc((size_t)B * T * C * 2);
  bf16* yb  = (bf16*)alloc((size_t)B * T * C * 2);
  bf16* wqkv_all = (bf16*)alloc((size_t)L * 3 * C * C * 2);
  bf16* wo_all   = (bf16*)alloc((size_t)L * C * C * 2);
  bf16* w1_all   = (bf16*)alloc((size_t)L * 3 * F * C * 2);
  bf16* w2_all   = (bf16*)alloc((size_t)L * 3 * C * F * 2);
  float* bqkv_all = (float*)alloc((size_t)L * 1536 * 4);
  (void)in_sizes; (void)n_in; (void)out_size; (void)ws_size;

  // ---- one-time prologue (consolidated; conversions 8-wide vectorized) ----
  {
    long tot = (long)B * 18 * (C + F) + (long)T * 16 + (long)L * 1536;
    prologue_misc_kernel<<<(int)((tot + 255) / 256), 256, 0, stream>>>(
        xm, hb, ropeC, ropeS, bq, bk, bv, bqkv_all);
  }
  transpose_in_kernel<<<dim3(T / 32, C / 32, B), dim3(32, 8), 0, stream>>>(xin, msk, x, xm);
  {
    long tot = (long)L * 3 * C * C / 8 + (long)L * C * C / 8;
    cvt_qkvo_kernel<<<(int)((tot + 255) / 256), 256, 0, stream>>>(
        Wq, Wk, Wv, Wo, wqkv_all, wo_all);
  }
  {
    long tot = (long)L * F * C / 8 + (long)L * C * F / 8;
    cvt_w12_kernel<<<(int)((tot + 255) / 256), 256, 0, stream>>>(
        W1, W2, w1_all, w2_all);
  }

  for (int i = 0; i < L; ++i) {
    const bf16* wqkv = wqkv_all + (long)i * 3 * C * C;
    const bf16* wo   = wo_all + (long)i * C * C;
    const bf16* w1b  = w1_all + (long)i * 3 * F * C;
    const bf16* w2b  = w2_all + (long)i * 3 * C * F;
    const float* bqkv = bqkv_all + (long)i * 1536;

    // fused QKV projection (N=1536) + RoPE in epilogue; v stored transposed
    gemm_kernel<64, 128, 1, 2, false, false, 1, false, false, 4, 64>
        <<<dim3(16, 12, B), 256, 0, stream>>>(
        xm + C, wqkv, bqkv, msk, q, k, vT,
        C, C, C, C, 0,
        (long)TP * C, 0, 0, 0, (long)T * C, 0, 0, ropeC, ropeS);

    flash_kernel<<<dim3(T / 64, B * H), 256, 0, stream>>>(q, k, vT, msk, o);

    // O projection (batch flattened: M = B*T) — BK=64
    gemm_kernel<64, 64, 1, 0, false, false, 1, false, false, 4, 64>
        <<<dim3(64, 8, 1), 256, 0, stream>>>(
        o, wo, bo + (size_t)i * C, msk, yb, nullptr, nullptr,
        C, C, C, C, 0,
        0, 0, 0, 0, 0, 0, 0, nullptr, nullptr);

    ln_kernel<<<B * T / 4, 256, 0, stream>>>(x, yb, g1 + (size_t)i * C, be1 + (size_t)i * C,
                                             msk, 1, 0, x, xm);

    // FFN conv1 (K=3, relu, masked output) — 128x128 tile, BK=32 (R10-proven)
    gemm_kernel<128, 128, 3, 0, true, true, 1, false, false, 2, 32>
        <<<dim3(8, 16, B), 256, 0, stream>>>(
        xm, w1b, c1 + (size_t)i * F, msk, hb + F, nullptr, nullptr,
        C, C, F, C, (long)F * C,
        (long)TP * C, 0, 0, 0, (long)TP * F, 0, 0, nullptr, nullptr);

    // FFN conv2 (K=3) — 64x64 tile, BK=64
    gemm_kernel<64, 64, 3, 0, false, false, 1, false, false, 2, 64>
        <<<dim3(16, 8, B), 256, 0, stream>>>(
        hb, w2b, c2 + (size_t)i * C, msk, yb, nullptr, nullptr,
        F, F, C, F, (long)C * F,
        (long)TP * F, 0, 0, 0, (long)T * C, 0, 0, nullptr, nullptr);

    ln_kernel<<<B * T / 4, 256, 0, stream>>>(x, yb, g2 + (size_t)i * C, be2 + (size_t)i * C,
                                             msk, 0, 1, x, xm);
  }

  transpose_out_kernel<<<dim3(T / 32, C / 32, B), dim3(32, 8), 0, stream>>>(x, msk, (float*)d_out);
}

// Round 20
// 763.633 us; speedup vs baseline: 1.0304x; 1.0008x over previous
//
#include <hip/hip_runtime.h>

typedef __bf16 bf16;
typedef __bf16 bf16x2 __attribute__((ext_vector_type(2)));
typedef __bf16 bf16x8 __attribute__((ext_vector_type(8)));
typedef __bf16 bf16x4v __attribute__((ext_vector_type(4)));
typedef float f32x4 __attribute__((ext_vector_type(4)));

constexpr int B = 4, C = 512, T = 1024, H = 8, F = 2048, L = 6;
constexpr int TP = T + 18;               // padded rows: row0 = zero, rows T+1..T+17 zero
constexpr float SCALE = 0.125f, EPS = 1e-4f;

// ---------------------------------------------------------------------------
// global -> LDS staging, 64B rows (BK=32 tiles: 32 bf16 k-slice per row)
// LDS linear; swizzle applied on the per-lane GLOBAL source (involution),
// matched by the same XOR on the ds_read side.
// ---------------------------------------------------------------------------
__device__ __forceinline__ void stage_rows(const char* g, long strideB, char* lds,
                                           int nChunks, int tid) {
  const int wave = tid >> 6, lane = tid & 63;
  for (int c = wave; c < nChunks; c += 4) {
    int row = (c << 4) + (lane >> 2);
    int kq = (lane & 3) ^ ((row >> 1) & 3);
    const char* src = g + (long)row * strideB + kq * 16;
    char* dst = lds + ((long)c << 10);
    __builtin_amdgcn_global_load_lds((const __attribute__((address_space(1))) void*)src,
                                     (__attribute__((address_space(3))) void*)dst,
                                     16, 0, 0);
  }
}

// 128B rows (BK=64 tiles / flash: 64 bf16 per row).
// LDS[row][slot16] = G[row][slot ^ (row&7)].
__device__ __forceinline__ void stage_rows128(const char* g, long strideB, char* lds,
                                              int nChunks, int tid) {
  const int wave = tid >> 6, lane = tid & 63;
  for (int c = wave; c < nChunks; c += 4) {
    int row = (c << 3) + (lane >> 3);
    int kq = (lane & 7) ^ ((lane >> 3) & 7);
    const char* src = g + (long)row * strideB + kq * 16;
    char* dst = lds + ((long)c << 10);
    __builtin_amdgcn_global_load_lds((const __attribute__((address_space(1))) void*)src,
                                     (__attribute__((address_space(3))) void*)dst,
                                     16, 0, 0);
  }
}

// ---------------------------------------------------------------------------
// NT GEMM, 2-phase prefetch double-buffered LDS (proven path).
// D[m][n] = sum_k A[m][k] * Bw[n][k]  (+ kw-shifted A rows for KW=3)
// BK: 32 (64B rows) or 64 (128B rows; halves barrier-drain events — proven
//     on FFN2 (R9) and QKV/oproj (R10); NOT at the cost of tile size (R11)).
// EPI: 0 = bf16 [m][ldo] (+bias, relu, maskM opts)
//      2 = QKV split with fused RoPE: n<512 -> O(q), <1024 -> O2(k),
//          else O3 = vT[n-1024][m]
// ---------------------------------------------------------------------------
template <int BM, int BN, int KW, int EPI, bool RELU, bool MASKM, int ZD,
          bool AZL, bool OZL, int MINW, int BK>
__global__ __launch_bounds__(256, MINW) void gemm_kernel(
    const bf16* __restrict__ A, const bf16* __restrict__ Bw,
    const float* __restrict__ bias, const float* __restrict__ mask,
    bf16* __restrict__ O, bf16* __restrict__ O2, bf16* __restrict__ O3,
    int lda, int ldb, int ldo, int K, long bSlice,
    long aZ1, long aZ2, long bZ1, long bZ2, long oZ1, long oZ2, int zoff,
    const float* __restrict__ ropeC, const float* __restrict__ ropeS)
{
  constexpr int WTM = BM / 2, WTN = BN / 2, FM = WTM / 16, FN = WTN / 16;
  constexpr int RA = (KW == 3) ? BM + 16 : BM;
  constexpr int ROWB = (BK == 64) ? 128 : 64;
  constexpr int ACH = RA * ROWB / 1024;
  constexpr int BCHS = BN * ROWB / 1024;
  constexpr int TCH = ACH + KW * BCHS;
  __shared__ __align__(1024) bf16 sBuf[2][TCH * 512];

  const int tid = threadIdx.x;
  const int zl = blockIdx.z, zg = zl + zoff;
  const int zb = zg / ZD, zh = zg % ZD;
  const long aOff = AZL ? (long)zl * aZ1 : (long)zb * aZ1 + (long)zh * aZ2;
  const long bOff = (long)zb * bZ1 + (long)zh * bZ2;
  const long oOff = OZL ? (long)zl * oZ1 : (long)zb * oZ1 + (long)zh * oZ2;
  const int m0 = blockIdx.x * BM, n0 = blockIdx.y * BN;
  const bf16* Ab = A + aOff + (long)m0 * lda;
  const bf16* Bb = Bw + bOff + (long)n0 * ldb;

  const int wid = tid >> 6, lane = tid & 63;
  const int wm = wid >> 1, wn = wid & 1;
  const int l16 = lane & 15, q4 = lane >> 4;

  f32x4 acc[FM][FN] = {};

  auto STAGE = [&](int k0, int buf) {
    char* sa = (char*)sBuf[buf];
    if constexpr (BK == 64) {
      stage_rows128((const char*)(Ab + k0), (long)lda * 2, sa, ACH, tid);
      #pragma unroll
      for (int kw = 0; kw < KW; ++kw)
        stage_rows128((const char*)(Bb + (long)kw * bSlice + k0), (long)ldb * 2,
                      sa + (ACH + kw * BCHS) * 1024, BCHS, tid);
    } else {
      stage_rows((const char*)(Ab + k0), (long)lda * 2, sa, ACH, tid);
      #pragma unroll
      for (int kw = 0; kw < KW; ++kw)
        stage_rows((const char*)(Bb + (long)kw * bSlice + k0), (long)ldb * 2,
                   sa + (ACH + kw * BCHS) * 1024, BCHS, tid);
    }
  };

  auto COMPUTE = [&](int buf) {
    const char* sa = (const char*)sBuf[buf];
    const char* sb = sa + ACH * 1024;
    if constexpr (BK == 64) {
      #pragma unroll
      for (int kw = 0; kw < KW; ++kw) {
        #pragma unroll
        for (int kk2 = 0; kk2 < 2; ++kk2) {
          bf16x8 af[FM], bfr[FN];
          #pragma unroll
          for (int fm = 0; fm < FM; ++fm) {
            const int row = wm * WTM + fm * 16 + l16 + (KW == 3 ? kw : 0);
            unsigned off = (unsigned)(kk2 * 64 + q4 * 16) ^ ((unsigned)(row & 7) << 4);
            af[fm] = *(const bf16x8*)(sa + row * 128 + off);
          }
          #pragma unroll
          for (int fn = 0; fn < FN; ++fn) {
            const int rn = wn * WTN + fn * 16 + l16;
            unsigned off = (unsigned)(kk2 * 64 + q4 * 16) ^ ((unsigned)(rn & 7) << 4);
            bfr[fn] = *(const bf16x8*)(sb + kw * BCHS * 1024 + rn * 128 + off);
          }
          #pragma unroll
          for (int fm = 0; fm < FM; ++fm)
            #pragma unroll
            for (int fn = 0; fn < FN; ++fn)
              acc[fm][fn] = __builtin_amdgcn_mfma_f32_16x16x32_bf16(af[fm], bfr[fn],
                                                                    acc[fm][fn], 0, 0, 0);
        }
      }
    } else {
      #pragma unroll
      for (int kw = 0; kw < KW; ++kw) {
        bf16x8 af[FM], bfr[FN];
        #pragma unroll
        for (int fm = 0; fm < FM; ++fm) {
          int row = wm * WTM + fm * 16 + l16 + (KW == 3 ? kw : 0);
          unsigned ad = (unsigned)(row * 64 + q4 * 16);
          ad ^= ((ad >> 7) & 3u) << 4;
          af[fm] = *(const bf16x8*)(sa + ad);
        }
        #pragma unroll
        for (int fn = 0; fn < FN; ++fn) {
          int rn = wn * WTN + fn * 16 + l16;
          unsigned bd = (unsigned)(rn * 64 + q4 * 16);
          bd ^= ((bd >> 7) & 3u) << 4;
          bfr[fn] = *(const bf16x8*)(sb + kw * BCHS * 1024 + bd);
        }
        #pragma unroll
        for (int fm = 0; fm < FM; ++fm)
          #pragma unroll
          for (int fn = 0; fn < FN; ++fn)
            acc[fm][fn] = __builtin_amdgcn_mfma_f32_16x16x32_bf16(af[fm], bfr[fn],
                                                                  acc[fm][fn], 0, 0, 0);
      }
    }
  };

  STAGE(0, 0);
  __syncthreads();
  int cur = 0;
  for (int k0 = BK; k0 < K; k0 += BK) {
    STAGE(k0, cur ^ 1);
    COMPUTE(cur);
    __syncthreads();
    cur ^= 1;
  }
  COMPUTE(cur);

  // ---- epilogue: C/D layout col=lane&15, row=(lane>>4)*4+i ----
  float varr[FN][FM][4];
  #pragma unroll
  for (int fn = 0; fn < FN; ++fn) {
    const int nl = n0 + wn * WTN + fn * 16 + l16;
    const float bv = (bias == nullptr) ? 0.f : bias[nl];
    #pragma unroll
    for (int fm = 0; fm < FM; ++fm) {
      const int mb = m0 + wm * WTM + fm * 16 + q4 * 4;
      #pragma unroll
      for (int i = 0; i < 4; ++i) {
        float t = acc[fm][fn][i] + bv;
        if (RELU) t = fmaxf(t, 0.f);
        if (MASKM) t *= mask[(long)zb * T + mb + i];
        varr[fn][fm][i] = t;
      }
    }
  }

  if constexpr (EPI == 2) {
    if (n0 + wn * WTN < 1024) {
      #pragma unroll
      for (int fm = 0; fm < FM; ++fm) {
        const int mb = m0 + wm * WTM + fm * 16 + q4 * 4;
        #pragma unroll
        for (int i = 0; i < 4; ++i) {
          const int t = mb + i;
          float cv = ropeC[t * 16 + l16], sv = ropeS[t * 16 + l16];
          float a = varr[0][fm][i], b2 = varr[1][fm][i];
          varr[0][fm][i] = a * cv - b2 * sv;
          varr[1][fm][i] = b2 * cv + a * sv;
        }
      }
    }
  }

  #pragma unroll
  for (int fn = 0; fn < FN; ++fn) {
    const int nl = n0 + wn * WTN + fn * 16 + l16;
    #pragma unroll
    for (int fm = 0; fm < FM; ++fm) {
      const int mb = m0 + wm * WTM + fm * 16 + q4 * 4;
      if constexpr (EPI == 2) {
        if (nl < 1024) {
          bf16* dst = (nl < 512 ? O : O2) + oOff + (nl & 511);
          #pragma unroll
          for (int i = 0; i < 4; ++i)
            dst[(long)(mb + i) * C] = (bf16)varr[fn][fm][i];
        } else {
          bf16x4v tv;
          #pragma unroll
          for (int i = 0; i < 4; ++i) tv[i] = (bf16)varr[fn][fm][i];
          *(bf16x4v*)(O3 + oOff + (long)(nl - 1024) * T + mb) = tv;
        }
      } else {
        bf16* dst = O + oOff;
        #pragma unroll
        for (int i = 0; i < 4; ++i)
          dst[(long)(mb + i) * ldo + nl] = (bf16)varr[fn][fm][i];
      }
    }
  }
}

// ---------------------------------------------------------------------------
// Flash attention: one block = 64 q-rows x one (b,h). 4 waves x 16 q-rows.
// XCD-aware work swizzle (T1). Fixed-base softmax: p = exp(s - 8).
// ---------------------------------------------------------------------------
__global__ __launch_bounds__(256, 3) void flash_kernel(
    const bf16* __restrict__ q, const bf16* __restrict__ k,
    const bf16* __restrict__ vT, const float* __restrict__ mask,
    bf16* __restrict__ o)
{
  __shared__ __align__(1024) char sQ[64 * 128];
  __shared__ __align__(1024) char sK[2][64 * 128];
  __shared__ __align__(1024) char sV[2][64 * 128];
  __shared__ __align__(1024) char sP[4][16 * 128];

  const int tid = threadIdx.x;
  const int w = tid >> 6, lane = tid & 63;
  const int l16 = lane & 15, q4 = lane >> 4;
  // dispatch-linear id -> XCD-chunked work id (bijective on 512 = 8*64)
  const int g = blockIdx.y * 16 + blockIdx.x;
  const int swz = (g & 7) * 64 + (g >> 3);
  const int q0 = (swz & 15) * 64;
  const int bh = swz >> 4;
  const int b = bh >> 3, h = bh & 7;

  const bf16* qb = q + ((long)b * T + q0) * C + h * 64;
  const bf16* kb = k + (long)b * T * C + h * 64;
  const bf16* vb = vT + (long)b * C * T + (long)h * 64 * T;

  stage_rows128((const char*)qb, (long)C * 2, sQ, 8, tid);
  stage_rows128((const char*)kb, (long)C * 2, sK[0], 8, tid);
  stage_rows128((const char*)vb, (long)T * 2, sV[0], 8, tid);
  __syncthreads();

  bf16x8 af_q[2];
  {
    const int r = w * 16 + l16;
    #pragma unroll
    for (int kk = 0; kk < 2; ++kk) {
      unsigned off = (unsigned)(kk * 64 + q4 * 16) ^ ((unsigned)(r & 7) << 4);
      af_q[kk] = *(const bf16x8*)(sQ + r * 128 + off);
    }
  }

  float mq[4];
  #pragma unroll
  for (int i = 0; i < 4; ++i)
    mq[i] = mask[(long)b * T + q0 + w * 16 + q4 * 4 + i];

  f32x4 accO[4] = {};
  float lrun[4] = {0.f, 0.f, 0.f, 0.f};   // per-lane partial row sums
  char* sPw = sP[w];

  int cur = 0;
  for (int it = 0; it < 16; ++it) {
    if (it < 15) {
      stage_rows128((const char*)(kb + (long)(it + 1) * 64 * C), (long)C * 2, sK[cur ^ 1], 8, tid);
      stage_rows128((const char*)(vb + (it + 1) * 64), (long)T * 2, sV[cur ^ 1], 8, tid);
    }
    f32x4 s[4] = {};
    #pragma unroll
    for (int kk = 0; kk < 2; ++kk) {
      #pragma unroll
      for (int fn = 0; fn < 4; ++fn) {
        const int rn = fn * 16 + l16;
        unsigned off = (unsigned)(kk * 64 + q4 * 16) ^ ((unsigned)(rn & 7) << 4);
        bf16x8 kf = *(const bf16x8*)(sK[cur] + rn * 128 + off);
        s[fn] = __builtin_amdgcn_mfma_f32_16x16x32_bf16(af_q[kk], kf, s[fn], 0, 0, 0);
      }
    }
    float mk[4];
    #pragma unroll
    for (int fn = 0; fn < 4; ++fn)
      mk[fn] = mask[(long)b * T + it * 64 + fn * 16 + l16];
    // fixed-base exp: p = exp(s*SCALE - 8); masked -> exp(-10008) = 0
    #pragma unroll
    for (int fn = 0; fn < 4; ++fn)
      #pragma unroll
      for (int i = 0; i < 4; ++i) {
        float xval = s[fn][i] * SCALE;
        float sv = (mq[i] * mk[fn] > 0.f) ? xval : -10000.f;
        float p = __expf(sv - 8.f);
        lrun[i] += p;
        const int row = q4 * 4 + i;
        unsigned off = (unsigned)((fn * 16 + l16) * 2) ^ ((unsigned)(row & 7) << 4);
        *(bf16*)(sPw + row * 128 + off) = (bf16)p;
      }
    #pragma unroll
    for (int kk = 0; kk < 2; ++kk) {
      unsigned poff = (unsigned)(kk * 64 + q4 * 16) ^ ((unsigned)(l16 & 7) << 4);
      bf16x8 pf = *(const bf16x8*)(sPw + l16 * 128 + poff);
      #pragma unroll
      for (int fn = 0; fn < 4; ++fn) {
        const int rn = fn * 16 + l16;
        unsigned off = (unsigned)(kk * 64 + q4 * 16) ^ ((unsigned)(rn & 7) << 4);
        bf16x8 vf = *(const bf16x8*)(sV[cur] + rn * 128 + off);
        accO[fn] = __builtin_amdgcn_mfma_f32_16x16x32_bf16(pf, vf, accO[fn], 0, 0, 0);
      }
    }
    __syncthreads();
    cur ^= 1;
  }

  // single end-of-loop row-sum reduction over the 16 l16 lanes
  float linv[4];
  #pragma unroll
  for (int i = 0; i < 4; ++i) {
    #pragma unroll
    for (int st = 1; st < 16; st <<= 1) lrun[i] += __shfl_xor(lrun[i], st, 64);
    linv[i] = 1.f / fmaxf(lrun[i], 1e-20f);   // guard fully-masked rows
  }
  #pragma unroll
  for (int fn = 0; fn < 4; ++fn)
    #pragma unroll
    for (int i = 0; i < 4; ++i)
      o[((long)b * T + q0 + w * 16 + q4 * 4 + i) * C + h * 64 + fn * 16 + l16] =
          (bf16)(accO[fn][i] * linv[i]);
}

// ---------------- fused residual + LayerNorm over contiguous C ----------------
// Residual stream x is bf16 (2% tolerance admits the ~0.2%/layer rounding;
// LN renormalizes each layer so errors don't compound multiplicatively).
__global__ __launch_bounds__(256) void ln_kernel(
    const bf16* __restrict__ x, const bf16* __restrict__ y,
    const float* __restrict__ gamma, const float* __restrict__ beta,
    const float* __restrict__ mask, int maskA, int maskY,
    bf16* __restrict__ xout, bf16* __restrict__ xm)
{
  const int w = threadIdx.x >> 6, lane = threadIdx.x & 63;
  const long row = (long)blockIdx.x * 4 + w;
  const int b = (int)(row >> 10), t = (int)(row & 1023);
  const bf16* xr = x + row * C;
  const bf16* yr = y + row * C;
  const float m = mask[(long)b * T + t];
  const float fa = maskA ? m : 1.f, fy = maskY ? m : 1.f;
  bf16x8 xv = *(const bf16x8*)(xr + lane * 8);
  bf16x8 yv = *(const bf16x8*)(yr + lane * 8);
  float vals[8];
  float sum = 0.f, sq = 0.f;
  #pragma unroll
  for (int i = 0; i < 8; ++i) {
    vals[i] = (float)xv[i] * fa + (float)yv[i] * fy;
    sum += vals[i]; sq += vals[i] * vals[i];
  }
  #pragma unroll
  for (int s = 1; s < 64; s <<= 1) {
    sum += __shfl_xor(sum, s, 64);
    sq  += __shfl_xor(sq, s, 64);
  }
  float mean = sum * (1.f / C);
  float rstd = rsqrtf(sq * (1.f / C) - mean * mean + EPS);
  float4 g0 = *(const float4*)(gamma + lane * 8), g1v = *(const float4*)(gamma + lane * 8 + 4);
  float4 b0 = *(const float4*)(beta + lane * 8),  b1v = *(const float4*)(beta + lane * 8 + 4);
  float gg[8] = {g0.x, g0.y, g0.z, g0.w, g1v.x, g1v.y, g1v.z, g1v.w};
  float bb[8] = {b0.x, b0.y, b0.z, b0.w, b1v.x, b1v.y, b1v.z, b1v.w};
  bf16x8 xov, xmv;
  #pragma unroll
  for (int i = 0; i < 8; ++i) {
    float o = (vals[i] - mean) * rstd * gg[i] + bb[i];
    xov[i] = (bf16)o;
    xmv[i] = (bf16)(o * m);
  }
  *(bf16x8*)(xout + row * C + lane * 8) = xov;
  *(bf16x8*)(xm + ((long)b * TP + t + 1) * C + lane * 8) = xmv;
}

// ---------------- transposes [b][C][T] <-> [b][t][C] ----------------
__global__ __launch_bounds__(256) void transpose_in_kernel(const float* __restrict__ xin,
                                                           const float* __restrict__ mask,
                                                           bf16* __restrict__ x,
                                                           bf16* __restrict__ xm) {
  __shared__ float tile[32][33];
  int tx = threadIdx.x, ty = threadIdx.y;
  int t0 = blockIdx.x * 32, c0 = blockIdx.y * 32, b = blockIdx.z;
  #pragma unroll
  for (int i = 0; i < 4; ++i)
    tile[ty + i * 8][tx] = xin[((long)b * C + c0 + ty + i * 8) * T + t0 + tx];
  __syncthreads();
  #pragma unroll
  for (int i = 0; i < 4; ++i) {
    int t = t0 + ty + i * 8;
    float val = tile[tx][ty + i * 8];
    float m = mask[(long)b * T + t];
    x[((long)b * T + t) * C + c0 + tx] = (bf16)val;
    xm[((long)b * TP + t + 1) * C + c0 + tx] = (bf16)(val * m);
  }
}

__global__ __launch_bounds__(256) void transpose_out_kernel(const bf16* __restrict__ x,
                                                            const float* __restrict__ mask,
                                                            float* __restrict__ out) {
  __shared__ float tile[32][33];
  int tx = threadIdx.x, ty = threadIdx.y;
  int t0 = blockIdx.x * 32, c0 = blockIdx.y * 32, b = blockIdx.z;
  #pragma unroll
  for (int i = 0; i < 4; ++i)
    tile[ty + i * 8][tx] = (float)x[((long)b * T + t0 + ty + i * 8) * C + c0 + tx];
  __syncthreads();
  #pragma unroll
  for (int i = 0; i < 4; ++i) {
    int t = t0 + tx;
    out[((long)b * C + c0 + ty + i * 8) * T + t] = tile[tx][ty + i * 8] * mask[(long)b * T + t];
  }
}

// ---------------------------------------------------------------------------
// Merged prologue misc: zero halo pads + RoPE table + bias concat (one grid,
// index-range dispatch; logic identical to the three former kernels).
// ---------------------------------------------------------------------------
__global__ __launch_bounds__(256) void prologue_misc_kernel(
    bf16* __restrict__ xm, bf16* __restrict__ hb,
    float* __restrict__ cosT, float* __restrict__ sinT,
    const float* __restrict__ bq, const float* __restrict__ bk,
    const float* __restrict__ bv, float* __restrict__ bqkv_all)
{
  const long n1 = (long)B * 18 * C;
  const long n2 = (long)B * 18 * F;
  const long nR = (long)T * 16;
  const long nB = (long)L * 1536;
  long idx = (long)blockIdx.x * 256 + threadIdx.x;
  if (idx < n1) {
    int c = (int)(idx % C); int r = (int)((idx / C) % 18); int b = (int)(idx / (18L * C));
    int p = (r == 0) ? 0 : (T + r);
    xm[((long)b * TP + p) * C + c] = (bf16)0.f;
  } else if (idx < n1 + n2) {
    long j = idx - n1;
    int c = (int)(j % F); int r = (int)((j / F) % 18); int b = (int)(j / (18L * F));
    int p = (r == 0) ? 0 : (T + r);
    hb[((long)b * TP + p) * F + c] = (bf16)0.f;
  } else if (idx < n1 + n2 + nR) {
    long j = idx - n1 - n2;
    int t = (int)(j >> 4), jj = (int)(j & 15);
    float theta = powf(10000.f, -(float)jj / 16.f);
    float s, c;
    sincosf((float)t * theta, &s, &c);
    cosT[j] = c;
    sinT[j] = s;
  } else if (idx < n1 + n2 + nR + nB) {
    long j2 = idx - n1 - n2 - nR;
    int j = (int)(j2 % 1536), i = (int)(j2 / 1536);
    float v = (j < 512) ? bq[i * 512 + j] : (j < 1024) ? bk[i * 512 + j - 512]
                                                       : bv[i * 512 + j - 1024];
    bqkv_all[j2] = v;
  }
}

// ---------------------------------------------------------------------------
// Merged square-weight conversion: qkv (interleaved [i][slot][n][c]) + wo.
// 8 floats/thread: 2x float4 read -> 1x bf16x8 (16B) write (lane-contiguous).
// ---------------------------------------------------------------------------
__global__ __launch_bounds__(256) void cvt_qkvo_kernel(
    const float* __restrict__ Wq, const float* __restrict__ Wk,
    const float* __restrict__ Wv, const float* __restrict__ Wo,
    bf16* __restrict__ wqkv_all, bf16* __restrict__ wo_all)
{
  const long nQ = (long)L * 3 * C * C / 8;
  const long nO = (long)L * C * C / 8;
  long idx = (long)blockIdx.x * 256 + threadIdx.x;
  if (idx < nQ) {
    int c8 = (int)(idx & 63) * 8;                 // C/8 = 64 c-groups
    int n = (int)((idx >> 6) & 511);
    int s2 = (int)(idx >> 15);                    // 512*64 = 2^15 per (i,slot)
    int slot = s2 % 3, i = s2 / 3;
    const float* src = (slot == 0 ? Wq : slot == 1 ? Wk : Wv) + (long)i * C * C + (long)n * C + c8;
    float4 a = *(const float4*)src;
    float4 b = *(const float4*)(src + 4);
    bf16x8 d = {(bf16)a.x, (bf16)a.y, (bf16)a.z, (bf16)a.w,
                (bf16)b.x, (bf16)b.y, (bf16)b.z, (bf16)b.w};
    *(bf16x8*)(wqkv_all + (((long)(i * 3 + slot) * 512 + n) * 512 + c8)) = d;
  } else if (idx < nQ + nO) {
    long j = idx - nQ;
    const float* src = Wo + j * 8;
    float4 a = *(const float4*)src;
    float4 b = *(const float4*)(src + 4);
    bf16x8 d = {(bf16)a.x, (bf16)a.y, (bf16)a.z, (bf16)a.w,
                (bf16)b.x, (bf16)b.y, (bf16)b.z, (bf16)b.w};
    *(bf16x8*)(wo_all + j * 8) = d;
  }
}

// ---------------------------------------------------------------------------
// Merged K=3 weight conversion via LDS deinterleave. Each block owns one
// 6144-float segment (= 4 rows of W1 [Kd=C] or 1 row of W2 [Kd=F]).
// Phase 1: 6x float4 loads, LANE-CONTIGUOUS per instruction (16 merged lines
//   vs 64 scattered requests of the direct-gather version — which measured
//   only 2.3 TB/s in R18/R19), convert to bf16 into LDS (k-interleaved).
// Phase 2: barrier; each thread gathers 3x bf16x8 from LDS at stride-3 and
//   stores lane-contiguous to the three k-planes.
// ---------------------------------------------------------------------------
__global__ __launch_bounds__(256) void cvt_w12_kernel(
    const float* __restrict__ W1, const float* __restrict__ W2,
    bf16* __restrict__ w1_all, bf16* __restrict__ w2_all)
{
  __shared__ bf16 lbuf[6144];
  const int nSeg1 = L * F / 4;                 // 3072 segments of 4 rows (W1)
  int seg = blockIdx.x;
  const float* src;
  bf16* dst;
  int Kd, N, rowsPerSeg;
  if (seg < nSeg1) {
    src = W1; dst = w1_all; Kd = C; N = F; rowsPerSeg = 4;
  } else {
    seg -= nSeg1;
    src = W2; dst = w2_all; Kd = F; N = C; rowsPerSeg = 1;
  }
  const int tid = threadIdx.x;
  const long base = (long)seg * 6144;          // floats
  // phase 1: lane-contiguous load + convert into LDS
  #pragma unroll
  for (int t = 0; t < 6; ++t) {
    float4 v = *(const float4*)(src + base + (long)(t * 256 + tid) * 4);
    bf16x4v d = {(bf16)v.x, (bf16)v.y, (bf16)v.z, (bf16)v.w};
    *(bf16x4v*)(lbuf + (t * 256 + tid) * 4) = d;
  }
  __syncthreads();
  // phase 2: deinterleave and store (lane-contiguous per k-plane)
  const int G = Kd >> 3;                       // c-groups per row (64 or 256)
  const int r = tid / G;                       // row within segment
  const int c8 = (tid % G) * 8;
  const long grow = (long)seg * rowsPerSeg + r;   // global row = i*N + n
  const int i2 = (int)(grow / N);
  const int n = (int)(grow % N);
  const long plane = (long)N * Kd;
  const int lrow = r * Kd * 3;
  #pragma unroll
  for (int kk = 0; kk < 3; ++kk) {
    bf16x8 d;
    #pragma unroll
    for (int j = 0; j < 8; ++j)
      d[j] = lbuf[lrow + 3 * (c8 + j) + kk];
    *(bf16x8*)(dst + (long)i2 * 3 * plane + (long)kk * plane + (long)n * Kd + c8) = d;
  }
}

// ---------------------------------------------------------------------------
extern "C" void kernel_launch(void* const* d_in, const int* in_sizes, int n_in,
                              void* d_out, int out_size, void* d_ws, size_t ws_size,
                              hipStream_t stream)
{
  const float* xin = (const float*)d_in[0];
  const float* msk = (const float*)d_in[1];
  const float* Wq  = (const float*)d_in[2];
  const float* bq  = (const float*)d_in[3];
  const float* Wk  = (const float*)d_in[4];
  const float* bk  = (const float*)d_in[5];
  const float* Wv  = (const float*)d_in[6];
  const float* bv  = (const float*)d_in[7];
  const float* Wo  = (const float*)d_in[8];
  const float* bo  = (const float*)d_in[9];
  const float* g1  = (const float*)d_in[10];
  const float* be1 = (const float*)d_in[11];
  const float* W1  = (const float*)d_in[12];
  const float* c1  = (const float*)d_in[13];
  const float* W2  = (const float*)d_in[14];
  const float* c2  = (const float*)d_in[15];
  const float* g2  = (const float*)d_in[16];
  const float* be2 = (const float*)d_in[17];

  size_t off = 0;
  char* base = (char*)d_ws;
  auto alloc = [&](size_t bytes) -> char* {
    char* r = base + off;
    off = (off + bytes + 1023) & ~(size_t)1023;
    return r;
  };
  bf16* x      = (bf16*)alloc((size_t)B * T * C * 2);     // bf16 residual stream
  float* ropeC = (float*)alloc((size_t)T * 16 * 4);
  float* ropeS = (float*)alloc((size_t)T * 16 * 4);
  bf16* xm  = (bf16*)alloc((size_t)B * TP * C * 2);
  bf16* hb  = (bf16*)alloc((size_t)B * TP * F * 2);
  bf16* q   = (bf16*)alloc((size_t)B * T * C * 2);
  bf16* k   = (bf16*)alloc((size_t)B * T * C * 2);
  bf16* vT  = (bf16*)alloc((size_t)B * T * C * 2);
  bf16* o   = (bf16*)alloc((size_t)B * T * C * 2);
  bf16* yb  = (bf16*)alloc((size_t)B * T * C * 2);
  bf16* wqkv_all = (bf16*)alloc((size_t)L * 3 * C * C * 2);
  bf16* wo_all   = (bf16*)alloc((size_t)L * C * C * 2);
  bf16* w1_all   = (bf16*)alloc((size_t)L * 3 * F * C * 2);
  bf16* w2_all   = (bf16*)alloc((size_t)L * 3 * C * F * 2);
  float* bqkv_all = (float*)alloc((size_t)L * 1536 * 4);
  (void)in_sizes; (void)n_in; (void)out_size; (void)ws_size;

  // ---- one-time prologue (consolidated; conversions coalesced) ----
  {
    long tot = (long)B * 18 * (C + F) + (long)T * 16 + (long)L * 1536;
    prologue_misc_kernel<<<(int)((tot + 255) / 256), 256, 0, stream>>>(
        xm, hb, ropeC, ropeS, bq, bk, bv, bqkv_all);
  }
  transpose_in_kernel<<<dim3(T / 32, C / 32, B), dim3(32, 8), 0, stream>>>(xin, msk, x, xm);
  {
    long tot = (long)L * 3 * C * C / 8 + (long)L * C * C / 8;
    cvt_qkvo_kernel<<<(int)((tot + 255) / 256), 256, 0, stream>>>(
        Wq, Wk, Wv, Wo, wqkv_all, wo_all);
  }
  {
    int nSeg = L * F / 4 + L * C;             // 3072 + 3072 blocks
    cvt_w12_kernel<<<nSeg, 256, 0, stream>>>(W1, W2, w1_all, w2_all);
  }

  for (int i = 0; i < L; ++i) {
    const bf16* wqkv = wqkv_all + (long)i * 3 * C * C;
    const bf16* wo   = wo_all + (long)i * C * C;
    const bf16* w1b  = w1_all + (long)i * 3 * F * C;
    const bf16* w2b  = w2_all + (long)i * 3 * C * F;
    const float* bqkv = bqkv_all + (long)i * 1536;

    // fused QKV projection (N=1536) + RoPE in epilogue; v stored transposed
    gemm_kernel<64, 128, 1, 2, false, false, 1, false, false, 4, 64>
        <<<dim3(16, 12, B), 256, 0, stream>>>(
        xm + C, wqkv, bqkv, msk, q, k, vT,
        C, C, C, C, 0,
        (long)TP * C, 0, 0, 0, (long)T * C, 0, 0, ropeC, ropeS);

    flash_kernel<<<dim3(T / 64, B * H), 256, 0, stream>>>(q, k, vT, msk, o);

    // O projection (batch flattened: M = B*T) — BK=64
    gemm_kernel<64, 64, 1, 0, false, false, 1, false, false, 4, 64>
        <<<dim3(64, 8, 1), 256, 0, stream>>>(
        o, wo, bo + (size_t)i * C, msk, yb, nullptr, nullptr,
        C, C, C, C, 0,
        0, 0, 0, 0, 0, 0, 0, nullptr, nullptr);

    ln_kernel<<<B * T / 4, 256, 0, stream>>>(x, yb, g1 + (size_t)i * C, be1 + (size_t)i * C,
                                             msk, 1, 0, x, xm);

    // FFN conv1 (K=3, relu, masked output) — 128x128 tile, BK=32 (R10-proven)
    gemm_kernel<128, 128, 3, 0, true, true, 1, false, false, 2, 32>
        <<<dim3(8, 16, B), 256, 0, stream>>>(
        xm, w1b, c1 + (size_t)i * F, msk, hb + F, nullptr, nullptr,
        C, C, F, C, (long)F * C,
        (long)TP * C, 0, 0, 0, (long)TP * F, 0, 0, nullptr, nullptr);

    // FFN conv2 (K=3) — 64x64 tile, BK=64
    gemm_kernel<64, 64, 3, 0, false, false, 1, false, false, 2, 64>
        <<<dim3(16, 8, B), 256, 0, stream>>>(
        hb, w2b, c2 + (size_t)i * C, msk, yb, nullptr, nullptr,
        F, F, C, F, (long)C * F,
        (long)TP * F, 0, 0, 0, (long)T * C, 0, 0, nullptr, nullptr);

    ln_kernel<<<B * T / 4, 256, 0, stream>>>(x, yb, g2 + (size_t)i * C, be2 + (size_t)i * C,
                                             msk, 0, 1, x, xm);
  }

  transpose_out_kernel<<<dim3(T / 32, C / 32, B), dim3(32, 8), 0, stream>>>(x, msk, (float*)d_out);
}